// Round 3
// baseline (277.486 us; speedup 1.0000x reference)
//
#include <hip/hip_runtime.h>

#define Bn 8
#define Ln 128
#define Hn 768
#define Pn 16
#define Dn 102
#define EPSF 1e-8f
#define NINF -1e30f

__device__ __forceinline__ float wred_sum(float v){
#pragma unroll
  for(int o=32;o>=1;o>>=1) v += __shfl_xor(v,o);
  return v;
}
__device__ __forceinline__ float wred_max(float v){
#pragma unroll
  for(int o=32;o>=1;o>>=1) v = fmaxf(v,__shfl_xor(v,o));
  return v;
}
// sum over the 4 hq-quarters in the p-in-lane layout (lane = p + 16*hq)
__device__ __forceinline__ float qred_sum(float v){
  v += __shfl_xor(v,16);
  v += __shfl_xor(v,32);
  return v;
}

// ---- workspace layout (float element offsets; total ~12.5 MB) ----
constexpr size_t SZ_MAT   = (size_t)Bn*Ln*Hn;              // 786432
constexpr size_t OFF_C1F  = 0;
constexpr size_t OFF_C2F  = OFF_C1F + SZ_MAT;
constexpr size_t OFF_COS  = OFF_C2F + SZ_MAT;              // B*L*L
constexpr size_t OFF_N1   = OFF_COS + (size_t)Bn*Ln*Ln;    // B*L
constexpr size_t OFF_N2   = OFF_N1 + (size_t)Bn*Ln;
constexpr size_t OFF_WN   = OFF_N2 + (size_t)Bn*Ln;        // 2*5*B*P*L
constexpr size_t OFF_W2T  = OFF_WN + (size_t)2*5*Bn*Pn*Ln; // 5*H*P [X][h][p]
constexpr size_t OFF_MVMAX  = OFF_W2T + (size_t)5*Hn*Pn;   // 2*B*L*P
constexpr size_t OFF_MVMEAN = OFF_MVMAX + (size_t)2*Bn*Ln*Pn;
constexpr size_t OFF_PART   = OFF_MVMEAN + (size_t)2*Bn*Ln*Pn; // B*L*P*32*2 (side1)
constexpr size_t OFF_PART2  = OFF_PART + (size_t)Bn*Ln*Pn*32*2; // B*L*P*2*2 (side0 j-halves)
constexpr size_t OFF_LENS   = OFF_PART2 + (size_t)Bn*Ln*Pn*4;   // 32 ints

__device__ __forceinline__ size_t wnIdx(int side,int X,int b,int p,int i){
  return ((((size_t)side*5 + X)*Bn + b)*Pn + p)*Ln + i;
}

// ---------------- k_prep: lengths + squared-weight tables ----------------
__global__ __launch_bounds__(256) void k_prep(
    const float* __restrict__ m1, const float* __restrict__ m2,
    const float* __restrict__ wff, const float* __restrict__ wfb,
    const float* __restrict__ wmp, const float* __restrict__ watt,
    const float* __restrict__ wmatt,
    float* __restrict__ W2T, int* __restrict__ lens){
  int t = threadIdx.x;
  if(blockIdx.x < 8){
    int b = blockIdx.x;
    __shared__ int cnt[2];
    if(t<2) cnt[t]=0;
    __syncthreads();
    if(t<Ln){
      if(m1[b*Ln+t]>0.5f) atomicAdd(&cnt[0],1);
      if(m2[b*Ln+t]>0.5f) atomicAdd(&cnt[1],1);
    }
    __syncthreads();
    if(t==0){
      lens[b]=cnt[0]; lens[8+b]=cnt[1];
      lens[16+b]=max(cnt[0]-1,0); lens[24+b]=max(cnt[1]-1,0);
    }
  } else {
    int idx = (blockIdx.x-8)*256 + t;     // < 5*768*16 = 61440
    const float* srcs[5] = {wff,wfb,wmp,watt,wmatt};
    int X = idx/(Pn*Hn);
    int r = idx%(Pn*Hn);
    int h = r/Pn, p = r%Pn;
    float w = srcs[X][p*Hn+h];
    W2T[idx] = w*w;                        // layout [X][h][p]
  }
}

// ---------------- k_rows: masked rows + norms + weighted norms ----------------
__global__ __launch_bounds__(256) void k_rows(
    const float* __restrict__ ctx1, const float* __restrict__ m1,
    const float* __restrict__ ctx2, const float* __restrict__ m2,
    const float* __restrict__ W2T,
    float* __restrict__ c1f, float* __restrict__ c2f,
    float* __restrict__ n1, float* __restrict__ n2, float* __restrict__ wn){
  int i = blockIdx.x, b = blockIdx.y, side = blockIdx.z;
  const float* ctx = side? ctx2 : ctx1;
  const float* msk = side? m2 : m1;
  float* dst = side? c2f : c1f;
  float* nD  = side? n2 : n1;
  int t = threadIdx.x, w=t>>6, l=t&63;
  float mk = msk[b*Ln+i];
  size_t base = ((size_t)(b*Ln+i))*Hn;
  float v[3];
#pragma unroll
  for(int k=0;k<3;k++){
    float x = ctx[base + t + 256*k] * mk;
    v[k]=x;
    dst[base + t + 256*k] = x;
  }
  __shared__ float red4[4];
  __shared__ float redW[64];
  float ss = v[0]*v[0]+v[1]*v[1]+v[2]*v[2];
  float sst = wred_sum(ss);
  if(l==0) red4[w]=sst;
  __syncthreads();
  if(t==0) nD[b*Ln+i] = sqrtf(fmaxf(red4[0]+red4[1]+red4[2]+red4[3],0.f));
  for(int X=0;X<5;++X){
    float acc[16];
#pragma unroll
    for(int p=0;p<16;p++) acc[p]=0.f;
#pragma unroll
    for(int k=0;k<3;k++){
      int h = t+256*k;
      float vv = v[k]*v[k];
      const float4* wq = (const float4*)(W2T + ((size_t)X*Hn + h)*Pn);
      float4 q0=wq[0],q1=wq[1],q2=wq[2],q3=wq[3];
      float wv[16]={q0.x,q0.y,q0.z,q0.w,q1.x,q1.y,q1.z,q1.w,
                    q2.x,q2.y,q2.z,q2.w,q3.x,q3.y,q3.z,q3.w};
#pragma unroll
      for(int p=0;p<16;p++) acc[p]=fmaf(wv[p],vv,acc[p]);
    }
    __syncthreads();
#pragma unroll
    for(int p=0;p<16;p++){
      float a = wred_sum(acc[p]);
      if(l==0) redW[w*16+p]=a;
    }
    __syncthreads();
    if(t<16){
      float s = redW[t]+redW[16+t]+redW[32+t]+redW[48+t];
      wn[wnIdx(side,X,b,t,i)] = s;
    }
    __syncthreads();
  }
}

// ---------------- k_mm: e-tensor + fused cos ----------------
// grid (Bn, 64): y = itile*2 + jh. 512 threads = (jl:64, ph:2, row:4).
// Round-2 lessons: (a) grid was 256 = 1 block/CU → occupancy hard-capped at 25%;
// (b) s_load weights in the loop forced lgkmcnt(0) drains (SMEM is out-of-order).
// Fix: j-split grid (512 blocks → 2 blocks/CU) + full 48KB weight table in LDS
// (wave-uniform ds_read_b128 broadcasts; in-order lgkm → counted waits possible).
// Post-loop, sW is dead and is aliased by the side1 row-combine buffer.
#define PADW 33
__global__ __launch_bounds__(512) void k_mm(
    const float* __restrict__ c1f, const float* __restrict__ c2f,
    const float* __restrict__ W2mp, const float* __restrict__ WN,
    const float* __restrict__ n1, const float* __restrict__ n2,
    const float* __restrict__ m1, const float* __restrict__ m2,
    float* __restrict__ cosM,
    float* __restrict__ part, float* __restrict__ part2){
  const int b = blockIdx.x;
  const int itile = blockIdx.y >> 1;       // 0..31
  const int jh = blockIdx.y & 1;           // j-half
  const int i0 = itile*4;
  const int t = threadIdx.x;
  const int jl = t & 63;
  const int j  = jh*64 + jl;               // global j
  const int wv = t >> 6;                   // 0..7
  const int ph = wv & 1, row = wv >> 2 ? (wv>>1) : (wv>>1); // row = wv>>1
  const int rowi = wv >> 1;                // 0..3
  const int phu  = __builtin_amdgcn_readfirstlane(ph);
  const int rowu = __builtin_amdgcn_readfirstlane(rowi);

  __shared__ float sA[4*Hn];               // 12 KB
  __shared__ float sW[Hn*Pn];              // 48 KB; aliased post-loop by sPbig
  float* sPbig = sW;                       // [4][64][PADW] padded (8448 floats)

  // ---- stage A-rows and the full mp weight table ----
  {
    const float4* c1q = (const float4*)(c1f + ((size_t)(b*Ln+i0))*Hn);
    float4* sA4 = (float4*)sA;
    for(int idx=t; idx<Hn; idx+=512) sA4[idx] = c1q[idx];          // 4*Hn/4
    const float4* wq4 = (const float4*)W2mp;
    float4* sW4 = (float4*)sW;
    for(int idx=t; idx<(Hn*Pn)/4; idx+=512) sW4[idx] = wq4[idx];   // 3072
  }
  __syncthreads();

  const float4* brow = (const float4*)(c2f + ((size_t)(b*Ln+j))*Hn);
  const float4* aR   = (const float4*)(sA + rowu*Hn);
  const float4* wR   = (const float4*)sW + phu*2;   // element (h*16 + ph*8)

  float acc[8];
#pragma unroll
  for(int pp=0;pp<8;pp++) acc[pp]=0.f;
  float dot=0.f;

#pragma unroll 2
  for(int hq=0; hq<Hn/4; ++hq){
    float4 a  = aR[hq];
    float4 bq = brow[hq];
#pragma unroll
    for(int d=0; d<4; ++d){
      float bv = (d==0)? bq.x : (d==1)? bq.y : (d==2)? bq.z : bq.w;
      float av = (d==0)? a.x  : (d==1)? a.y  : (d==2)? a.z  : a.w;
      float pr = av*bv;
      dot += pr;
      float4 w0 = wR[(hq*4+d)*4];
      float4 w1 = wR[(hq*4+d)*4 + 1];
      acc[0]=fmaf(w0.x,pr,acc[0]); acc[1]=fmaf(w0.y,pr,acc[1]);
      acc[2]=fmaf(w0.z,pr,acc[2]); acc[3]=fmaf(w0.w,pr,acc[3]);
      acc[4]=fmaf(w1.x,pr,acc[4]); acc[5]=fmaf(w1.y,pr,acc[5]);
      acc[6]=fmaf(w1.z,pr,acc[6]); acc[7]=fmaf(w1.w,pr,acc[7]);
    }
  }

  const int iR = i0 + rowi;

  // ---- fused cosine write (ph==0 waves own it) ----
  if(ph==0){
    float nj = fmaxf(n2[b*Ln+j], EPSF);
    cosM[((size_t)(b*Ln+iR))*Ln + j] = dot/(fmaxf(n1[b*Ln+iR],EPSF)*nj);
  }

  // ---- normalize e in place ----
#pragma unroll
  for(int pp=0;pp<8;pp++){
    int p = ph*8+pp;
    float sl = sqrtf(fmaxf(WN[wnIdx(1,2,b,p,j)],0.f));
    float sr = sqrtf(fmaxf(WN[wnIdx(0,2,b,p,iR)],0.f));
    acc[pp] = acc[pp]/fmaxf(sr*sl,EPSF);
  }

  // ---- side0 partial: reduce over this block's 64 j-lanes (mask2) ----
  {
    const bool valid = (m2[b*Ln+j]!=0.f);
#pragma unroll
    for(int pp=0;pp<8;pp++){
      float vmax = valid? acc[pp] : NINF;
      float vsum = valid? acc[pp] : 0.f;
      vmax = wred_max(vmax);
      vsum = wred_sum(vsum);
      if(jl==0){
        size_t o = (((size_t)(b*Ln+iR))*Pn + ph*8+pp)*4 + jh*2;
        part2[o]   = vmax;
        part2[o+1] = vsum;
      }
    }
  }

  // ---- side1 partial: max/sum over the 4 i-rows (mask1), via aliased LDS ----
  __syncthreads();                       // all sW reads done before alias write
  {
    float mr = m1[b*Ln+iR];
#pragma unroll
    for(int pp=0;pp<8;pp++){
      int p = ph*8+pp;
      float mx = (mr!=0.f)? acc[pp] : NINF;
      float sm = (mr!=0.f)? acc[pp] : 0.f;
      sPbig[(rowi*64 + jl)*PADW + p*2    ] = mx;
      sPbig[(rowi*64 + jl)*PADW + p*2 + 1] = sm;
    }
  }
  __syncthreads();
  for(int s=t; s<64*16; s+=512){
    int jj = s>>4, p = s&15;
    float M=NINF, S=0.f;
#pragma unroll
    for(int r=0;r<4;r++){
      M = fmaxf(M, sPbig[(r*64+jj)*PADW + p*2]);
      S += sPbig[(r*64+jj)*PADW + p*2 + 1];
    }
    int jg = jh*64 + jj;
    size_t o = ((((size_t)(b*Ln+jg))*Pn + p)*32 + itile)*2;
    part[o]=M; part[o+1]=S;
  }
}

// ---------------- k_mm2: combine side1 partials (32 i-tiles) + side0 (2 j-halves) ----------------
__global__ __launch_bounds__(256) void k_mm2(
    const float* __restrict__ part, const float* __restrict__ part2,
    const int* __restrict__ lens,
    float* __restrict__ mvmax, float* __restrict__ mvmean){
  int g = blockIdx.x*256 + threadIdx.x;   // 16384 = B*L*P
  int b = g>>11;
  // side 1: over 32 i-tiles
  const float4* q = (const float4*)(part + (size_t)g*64);
  float mx = NINF, sm = 0.f;
#pragma unroll
  for(int k=0;k<16;k++){
    float4 v = q[k];
    mx = fmaxf(mx, fmaxf(v.x, v.z));
    sm += v.y + v.w;
  }
  int len1 = min(max(lens[b],1),Ln);
  size_t o1 = (size_t)Bn*Ln*Pn + g;       // side 1 block of mv arrays
  mvmax[o1] = mx;
  mvmean[o1] = sm/(float)len1;
  // side 0: over 2 j-halves
  float4 v2 = *(const float4*)(part2 + (size_t)g*4);
  int len2 = min(max(lens[8+b],1),Ln);
  mvmax[g]  = fmaxf(v2.x, v2.z);
  mvmean[g] = (v2.y + v2.w)/(float)len2;
}

// ---------------- k_fin: attention + all 102 features; p-in-lane Phase B ----------------
// grid (16, Ln/2): x = side*8+b → XCD = b
__global__ __launch_bounds__(256) void k_fin(
    const float* __restrict__ c1f, const float* __restrict__ c2f,
    const float* __restrict__ cosM,
    const float* __restrict__ n1, const float* __restrict__ n2,
    const float* __restrict__ wn, const float* __restrict__ W2T,
    const float* __restrict__ mvmax, const float* __restrict__ mvmean,
    const int* __restrict__ lens,
    const float* __restrict__ m1, const float* __restrict__ m2,
    float* __restrict__ out){
  const int x = blockIdx.x, side = x>>3, b = x&7;
  const int r0 = blockIdx.y*2;
  const int t = threadIdx.x, w = t>>6, l = t&63;
  const float* selfF  = side? c2f : c1f;
  const float* otherF = side? c1f : c2f;
  const float* nSelf  = side? n2 : n1;
  const float* nOther = side? n1 : n2;
  const float* mInner = side? m1 : m2;
  const float* mSelfm = side? m2 : m1;
  int lenI = side? lens[b]    : lens[8+b];
  int lpO  = side? lens[16+b] : lens[24+b];
  lenI = min(max(lenI,1),Ln);
  lpO  = min(max(lpO,0),Ln-1);

  __shared__ float cS[2*Ln];
  __shared__ float mS[Ln];
  __shared__ float sV1[2][Hn];
  __shared__ float sF[Hn], sB[Hn];
  __shared__ float sAS[2][Hn], sAM[2][Hn];
  __shared__ float red[8][4];

  // ---- stage ----
  {
    if(side==0){
      const float* crow = cosM + ((size_t)(b*Ln+r0))*Ln;
      for(int idx=t; idx<2*Ln; idx+=256) cS[idx]=crow[idx];
    } else {
      int jj = t&127, rp = t>>7;   // transposed read: cos^T[r][j] = cosM[j][r]
      cS[rp*Ln+jj] = cosM[((size_t)(b*Ln+jj))*Ln + r0+rp];
    }
    if(t<Ln) mS[t]=mInner[b*Ln+t];
    const float4* s4 = (const float4*)(selfF + ((size_t)(b*Ln+r0))*Hn);
    float4* d4 = (float4*)sV1;
    for(int idx=t; idx<2*Hn/4; idx+=256) d4[idx]=s4[idx];
    const float4* f4 = (const float4*)(otherF + ((size_t)(b*Ln+lpO))*Hn);
    const float4* b4 = (const float4*)(otherF + ((size_t)(b*Ln))*Hn);
    if(t<Hn/4){ ((float4*)sF)[t]=f4[t]; ((float4*)sB)[t]=b4[t]; }
  }
  __syncthreads();

  // ---- attention accumulation (2 rows, h = 3t..3t+2) ----
  float aS0[3]={0,0,0}, aS1[3]={0,0,0}, aM0[3]={NINF,NINF,NINF}, aM1[3]={NINF,NINF,NINF};
  {
    const float* src = otherF + (size_t)b*Ln*Hn;
#pragma unroll 4
    for(int jj=0; jj<Ln; ++jj){
      float3 vk = ((const float3*)(src + (size_t)jj*Hn))[t];
      float msk = mS[jj];
      float c0=cS[jj], c1v=cS[Ln+jj];
      aS0[0]=fmaf(vk.x,c0 ,aS0[0]); aS0[1]=fmaf(vk.y,c0 ,aS0[1]); aS0[2]=fmaf(vk.z,c0 ,aS0[2]);
      aS1[0]=fmaf(vk.x,c1v,aS1[0]); aS1[1]=fmaf(vk.y,c1v,aS1[1]); aS1[2]=fmaf(vk.z,c1v,aS1[2]);
      if(msk!=0.f){
        aM0[0]=fmaxf(aM0[0],vk.x*c0 ); aM0[1]=fmaxf(aM0[1],vk.y*c0 ); aM0[2]=fmaxf(aM0[2],vk.z*c0 );
        aM1[0]=fmaxf(aM1[0],vk.x*c1v); aM1[1]=fmaxf(aM1[1],vk.y*c1v); aM1[2]=fmaxf(aM1[2],vk.z*c1v);
      }
    }
  }

  // ---- softmax over h (2 rows); -1e30 masking => fully-masked rows → uniform ----
  {
    float lm0 = fmaxf(fmaxf(aS0[0],aS0[1]),aS0[2]);
    float lm1 = fmaxf(fmaxf(aS1[0],aS1[1]),aS1[2]);
    lm0 = wred_max(lm0); lm1 = wred_max(lm1);
    if(l==0){ red[0][w]=lm0; red[1][w]=lm1; }
  }
  __syncthreads();
  float bm0 = fmaxf(fmaxf(red[0][0],red[0][1]),fmaxf(red[0][2],red[0][3]));
  float bm1 = fmaxf(fmaxf(red[1][0],red[1][1]),fmaxf(red[1][2],red[1][3]));
  __syncthreads();
  float ev0[3], ev1[3];
  {
    float es0=0.f, es1=0.f;
#pragma unroll
    for(int k=0;k<3;k++){
      ev0[k]=expf(aS0[k]-bm0); es0+=ev0[k];
      ev1[k]=expf(aS1[k]-bm1); es1+=ev1[k];
    }
    es0 = wred_sum(es0); es1 = wred_sum(es1);
    if(l==0){ red[0][w]=es0; red[1][w]=es1; }
  }
  __syncthreads();
  {
    float smr0 = mSelfm[b*Ln+r0], smr1 = mSelfm[b*Ln+r0+1];
    float bs0 = red[0][0]+red[0][1]+red[0][2]+red[0][3];
    float bs1 = red[1][0]+red[1][1]+red[1][2]+red[1][3];
    float inv0 = 1.f/fmaxf(bs0,EPSF), inv1 = 1.f/fmaxf(bs1,EPSF);
    const float u = 1.f/(float)Hn;
#pragma unroll
    for(int k=0;k<3;k++){
      sAS[0][3*t+k] = (smr0!=0.f)? ev0[k]*inv0 : u;
      sAS[1][3*t+k] = (smr1!=0.f)? ev1[k]*inv1 : u;
      sAM[0][3*t+k] = aM0[k];
      sAM[1][3*t+k] = aM1[k];
    }
  }
  __syncthreads();

  // ---- Phase A (waves 0-1) + Phase C (wave 2): independent, no barrier ----
  if(w<2){
    int rr = w;
    float cmx=NINF, csm=0.f;
    float ca = cS[rr*Ln + l], cb = cS[rr*Ln + l + 64];
    if(mS[l]!=0.f){ cmx=ca; csm=ca; }
    if(mS[l+64]!=0.f){ cmx=fmaxf(cmx,cb); csm+=cb; }
    cmx = wred_max(cmx); csm = wred_sum(csm);
    if(l==0){
      float* op = out + ((size_t)((b*2+side)*Ln + r0+rr))*Dn;
      op[0] = cmx;
      op[1] = csm/(float)lenI;
    }
  } else if(w==2){
    int rr = l>>5, qq = l&31, p = qq&15;
    size_t o = ((size_t)((side*Bn+b)*Ln + r0+rr))*Pn + p;
    float* op = out + ((size_t)((b*2+side)*Ln + r0+rr))*Dn;
    if(qq<16) op[36+p] = mvmax[o];
    else      op[52+p] = mvmean[o];
  }

  // ---- Phase B: wave w handles mi=w for both rows; lane = (p, hq) ----
  {
    const int Xids[4] = {0,1,3,4};
    const int offS[4] = {2,19,68,85};
    const int X = Xids[w], offs = offS[w];
    const bool dyn = (w>=2);
    const int p = l&15, hq = l>>4;
    const int h0 = hq*192;
    const float* w2p = W2T + ((size_t)X*Hn)*Pn + p;
    float acc0=0.f, acc1=0.f, s00=0.f, s01=0.f;
    float sn0=0.f, sn1=0.f, sna0=0.f, sna1=0.f;
    if(!dyn){
      const float* bvp = (w==0)? sF : sB;
#pragma unroll 4
      for(int hh=0; hh<192; ++hh){
        int h = h0+hh;
        float w2v = w2p[(size_t)h*Pn];
        float bv = bvp[h];
        float pr0 = sV1[0][h]*bv, pr1 = sV1[1][h]*bv;
        acc0 = fmaf(w2v,pr0,acc0); acc1 = fmaf(w2v,pr1,acc1);
        s00 += pr0; s01 += pr1;
      }
    } else {
      const float* bv0p = (w==2)? sAS[0] : sAM[0];
      const float* bv1p = (w==2)? sAS[1] : sAM[1];
#pragma unroll 4
      for(int hh=0; hh<192; ++hh){
        int h = h0+hh;
        float w2v = w2p[(size_t)h*Pn];
        float bv0 = bv0p[h], bv1 = bv1p[h];
        float pr0 = sV1[0][h]*bv0, pr1 = sV1[1][h]*bv1;
        float bb0 = bv0*bv0, bb1 = bv1*bv1;
        acc0 = fmaf(w2v,pr0,acc0); acc1 = fmaf(w2v,pr1,acc1);
        sna0 = fmaf(w2v,bb0,sna0); sna1 = fmaf(w2v,bb1,sna1);
        s00 += pr0; s01 += pr1;
        sn0 += bb0; sn1 += bb1;
      }
    }
    acc0 = qred_sum(acc0); acc1 = qred_sum(acc1);
    s00  = qred_sum(s00);  s01  = qred_sum(s01);
    if(dyn){
      sna0 = qred_sum(sna0); sna1 = qred_sum(sna1);
      sn0  = qred_sum(sn0);  sn1  = qred_sum(sn1);
    }
#pragma unroll
    for(int rr=0; rr<2; ++rr){
      const int r = r0+rr;
      float accv = rr? acc1 : acc0;
      float s0v  = rr? s01  : s00;
      float snav = rr? sna1 : sna0;
      float snv  = rr? sn1  : sn0;
      float* op = out + ((size_t)((b*2+side)*Ln + r))*Dn;
      if(l<16){
        float wa = fmaxf(wn[wnIdx(side,X,b,l,r)],0.f);
        float wb = dyn? fmaxf(snav,0.f)
                      : fmaxf(wn[wnIdx(1-side,X,b,l,(w==0? lpO:0))],0.f);
        float mul = accv/(fmaxf(sqrtf(wa),EPSF)*fmaxf(sqrtf(wb),EPSF));
        op[offs+1+l] = mul;
      }
      if(l==0){
        float nb = dyn? sqrtf(fmaxf(snv,0.f)) : nOther[b*Ln + (w==0? lpO : 0)];
        float nv1 = nSelf[b*Ln+r];
        op[offs] = s0v/(fmaxf(nv1,EPSF)*fmaxf(nb,EPSF));
      }
    }
  }
}

extern "C" void kernel_launch(void* const* d_in, const int* in_sizes, int n_in,
                              void* d_out, int out_size, void* d_ws, size_t ws_size,
                              hipStream_t stream) {
  const float* ctx1 = (const float*)d_in[0];
  const float* m1   = (const float*)d_in[1];
  const float* ctx2 = (const float*)d_in[2];
  const float* m2   = (const float*)d_in[3];
  const float* wff  = (const float*)d_in[4];
  const float* wfb  = (const float*)d_in[5];
  const float* wmp  = (const float*)d_in[6];
  const float* watt = (const float*)d_in[7];
  const float* wmatt= (const float*)d_in[8];
  float* out = (float*)d_out;
  float* W = (float*)d_ws;
  int* lens = (int*)(W + OFF_LENS);

  k_prep<<<dim3(8 + (5*Pn*Hn)/256), 256, 0, stream>>>(m1,m2,wff,wfb,wmp,watt,wmatt,
      W+OFF_W2T, lens);
  k_rows<<<dim3(Ln,Bn,2), 256, 0, stream>>>(ctx1,m1,ctx2,m2, W+OFF_W2T,
      W+OFF_C1F, W+OFF_C2F, W+OFF_N1, W+OFF_N2, W+OFF_WN);
  k_mm<<<dim3(Bn, 64), 512, 0, stream>>>(W+OFF_C1F, W+OFF_C2F,
      W+OFF_W2T + (size_t)2*Hn*Pn, W+OFF_WN, W+OFF_N1, W+OFF_N2,
      m1, m2, W+OFF_COS, W+OFF_PART, W+OFF_PART2);
  k_mm2<<<dim3((Bn*Ln*Pn)/256), 256, 0, stream>>>(W+OFF_PART, W+OFF_PART2, lens,
      W+OFF_MVMAX, W+OFF_MVMEAN);
  k_fin<<<dim3(16, Ln/2), 256, 0, stream>>>(W+OFF_C1F, W+OFF_C2F, W+OFF_COS,
      W+OFF_N1, W+OFF_N2, W+OFF_WN, W+OFF_W2T, W+OFF_MVMAX, W+OFF_MVMEAN,
      lens, m1, m2, out);
}

// Round 4
// 258.256 us; speedup vs baseline: 1.0745x; 1.0745x over previous
//
#include <hip/hip_runtime.h>

#define Bn 8
#define Ln 128
#define Hn 768
#define Pn 16
#define Dn 102
#define EPSF 1e-8f
#define NINF -1e30f

__device__ __forceinline__ float wred_sum(float v){
#pragma unroll
  for(int o=32;o>=1;o>>=1) v += __shfl_xor(v,o);
  return v;
}
__device__ __forceinline__ float wred_max(float v){
#pragma unroll
  for(int o=32;o>=1;o>>=1) v = fmaxf(v,__shfl_xor(v,o));
  return v;
}
// sum over the 4 hq-quarters in the p-in-lane layout (lane = p + 16*hq)
__device__ __forceinline__ float qred_sum(float v){
  v += __shfl_xor(v,16);
  v += __shfl_xor(v,32);
  return v;
}

// ---- workspace layout (float element offsets; total ~12.2 MB) ----
constexpr size_t SZ_MAT   = (size_t)Bn*Ln*Hn;              // 786432
constexpr size_t OFF_C1F  = 0;
constexpr size_t OFF_C2F  = OFF_C1F + SZ_MAT;
constexpr size_t OFF_COS  = OFF_C2F + SZ_MAT;              // B*L*L
constexpr size_t OFF_N1   = OFF_COS + (size_t)Bn*Ln*Ln;    // B*L
constexpr size_t OFF_N2   = OFF_N1 + (size_t)Bn*Ln;
constexpr size_t OFF_WN   = OFF_N2 + (size_t)Bn*Ln;        // 2*5*B*P*L
constexpr size_t OFF_W2T  = OFF_WN + (size_t)2*5*Bn*Pn*Ln; // 5*H*P [X][h][p]
constexpr size_t OFF_MVMAX  = OFF_W2T + (size_t)5*Hn*Pn;   // 2*B*L*P
constexpr size_t OFF_MVMEAN = OFF_MVMAX + (size_t)2*Bn*Ln*Pn;
constexpr size_t OFF_PART   = OFF_MVMEAN + (size_t)2*Bn*Ln*Pn; // B*L*P*32*2
constexpr size_t OFF_LENS   = OFF_PART + (size_t)Bn*Ln*Pn*32*2; // 32 ints

__device__ __forceinline__ size_t wnIdx(int side,int X,int b,int p,int i){
  return ((((size_t)side*5 + X)*Bn + b)*Pn + p)*Ln + i;
}

// ---------------- k_prep: lengths + squared-weight tables ----------------
__global__ __launch_bounds__(256) void k_prep(
    const float* __restrict__ m1, const float* __restrict__ m2,
    const float* __restrict__ wff, const float* __restrict__ wfb,
    const float* __restrict__ wmp, const float* __restrict__ watt,
    const float* __restrict__ wmatt,
    float* __restrict__ W2T, int* __restrict__ lens){
  int t = threadIdx.x;
  if(blockIdx.x < 8){
    int b = blockIdx.x;
    __shared__ int cnt[2];
    if(t<2) cnt[t]=0;
    __syncthreads();
    if(t<Ln){
      if(m1[b*Ln+t]>0.5f) atomicAdd(&cnt[0],1);
      if(m2[b*Ln+t]>0.5f) atomicAdd(&cnt[1],1);
    }
    __syncthreads();
    if(t==0){
      lens[b]=cnt[0]; lens[8+b]=cnt[1];
      lens[16+b]=max(cnt[0]-1,0); lens[24+b]=max(cnt[1]-1,0);
    }
  } else {
    int idx = (blockIdx.x-8)*256 + t;     // < 5*768*16 = 61440
    const float* srcs[5] = {wff,wfb,wmp,watt,wmatt};
    int X = idx/(Pn*Hn);
    int r = idx%(Pn*Hn);
    int h = r/Pn, p = r%Pn;
    float w = srcs[X][p*Hn+h];
    W2T[idx] = w*w;                        // layout [X][h][p]
  }
}

// ---------------- k_rows: masked rows + norms + weighted norms ----------------
__global__ __launch_bounds__(256) void k_rows(
    const float* __restrict__ ctx1, const float* __restrict__ m1,
    const float* __restrict__ ctx2, const float* __restrict__ m2,
    const float* __restrict__ W2T,
    float* __restrict__ c1f, float* __restrict__ c2f,
    float* __restrict__ n1, float* __restrict__ n2, float* __restrict__ wn){
  int i = blockIdx.x, b = blockIdx.y, side = blockIdx.z;
  const float* ctx = side? ctx2 : ctx1;
  const float* msk = side? m2 : m1;
  float* dst = side? c2f : c1f;
  float* nD  = side? n2 : n1;
  int t = threadIdx.x, w=t>>6, l=t&63;
  float mk = msk[b*Ln+i];
  size_t base = ((size_t)(b*Ln+i))*Hn;
  float v[3];
#pragma unroll
  for(int k=0;k<3;k++){
    float x = ctx[base + t + 256*k] * mk;
    v[k]=x;
    dst[base + t + 256*k] = x;
  }
  __shared__ float red4[4];
  __shared__ float redW[64];
  float ss = v[0]*v[0]+v[1]*v[1]+v[2]*v[2];
  float sst = wred_sum(ss);
  if(l==0) red4[w]=sst;
  __syncthreads();
  if(t==0) nD[b*Ln+i] = sqrtf(fmaxf(red4[0]+red4[1]+red4[2]+red4[3],0.f));
  for(int X=0;X<5;++X){
    float acc[16];
#pragma unroll
    for(int p=0;p<16;p++) acc[p]=0.f;
#pragma unroll
    for(int k=0;k<3;k++){
      int h = t+256*k;
      float vv = v[k]*v[k];
      const float4* wq = (const float4*)(W2T + ((size_t)X*Hn + h)*Pn);
      float4 q0=wq[0],q1=wq[1],q2=wq[2],q3=wq[3];
      float wv[16]={q0.x,q0.y,q0.z,q0.w,q1.x,q1.y,q1.z,q1.w,
                    q2.x,q2.y,q2.z,q2.w,q3.x,q3.y,q3.z,q3.w};
#pragma unroll
      for(int p=0;p<16;p++) acc[p]=fmaf(wv[p],vv,acc[p]);
    }
    __syncthreads();
#pragma unroll
    for(int p=0;p<16;p++){
      float a = wred_sum(acc[p]);
      if(l==0) redW[w*16+p]=a;
    }
    __syncthreads();
    if(t<16){
      float s = redW[t]+redW[16+t]+redW[32+t]+redW[48+t];
      wn[wnIdx(side,X,b,t,i)] = s;
    }
    __syncthreads();
  }
}

// ---------------- k_mm: e-tensor + fused cos; side0 in-block, side1 partials ----------------
// grid (Bn, Ln/4), 512 threads = (j:128, ph:2, ih:2). XCD = b.
// Round-3 lessons: weights must stay on the SMEM (s_load) pipe — LDS'ing them
// oversubscribed the LDS pipe (9 ds_read_b128/hq vs 80cy VALU → VALUBusy 39%).
// Round-0/2 ceiling (VALUBusy 43%) was the per-hq exposed L2 latency of the
// global brow load (VGPR=32 → no pipelining, vmcnt(0) per iteration).
// Fix (T14/§5): stage B in 64-h chunks into double-buffered padded LDS via
// global→reg→ds_write; loads for chunk c+1 are issued BEFORE computing chunk c
// (~2560 cy of cover), so global latency is amortized to ~0 per hq.
#define HC 64                  // h per chunk
#define NCH (Hn/HC)            // 12 chunks
#define QCH (HC/4)             // 16 float4 per row per chunk
#define SBST 68                // padded row stride (floats): bank-rotate by 4/row
#define SBUFSZ (128*SBST)      // 8704 floats per buffer

__global__ __launch_bounds__(512) void k_mm(
    const float* __restrict__ c1f, const float* __restrict__ c2f,
    const float* __restrict__ W2mp, const float* __restrict__ WN,
    const float* __restrict__ n1, const float* __restrict__ n2,
    const float* __restrict__ m1, const float* __restrict__ m2,
    const int* __restrict__ lens,
    float* __restrict__ cosM,
    float* __restrict__ mvmax, float* __restrict__ mvmean,
    float* __restrict__ part){
  const int b = blockIdx.x;
  const int i0 = blockIdx.y*4;
  const int t = threadIdx.x;
  const int j = t&127, ph = (t>>7)&1, ih = t>>8;
  const int phu = __builtin_amdgcn_readfirstlane(ph);   // wave-uniform → SGPR
  const int ihu = __builtin_amdgcn_readfirstlane(ih);

  // LDS pool with aliasing: {sA,sB} live during K-loop (80 KB);
  // {sP,redR} alias sB after the loop (barrier-separated).
  __shared__ __align__(16) float pool[3072 + 2*SBUFSZ];   // 81,920 B
  float* sA = pool;                                        // 4*Hn
  float* sB = pool + 3072;                                 // 2*SBUFSZ
  float (*sP)[16][2]    = (float(*)[16][2])(pool + 3072);        // [128][16][2]
  float (*redR)[2][8][2]= (float(*)[2][8][2])(pool + 3072 + 4096); // [8][2][8][2]

  const float4* ball = (const float4*)(c2f + (size_t)b*Ln*Hn);

  // ---- prologue: stage A-rows + chunk 0 of B ----
  {
    const float4* arow4 = (const float4*)(c1f + ((size_t)(b*Ln+i0))*Hn);
    float4* sA4 = (float4*)sA;
    for(int idx=t; idx<Hn; idx+=512) sA4[idx] = arow4[idx];  // 4 rows = 768 float4
    float4 r[4];
#pragma unroll
    for(int k=0;k<4;k++){
      int s = k*512+t, jj = s>>4, q = s&15;
      r[k] = ball[(size_t)jj*(Hn/4) + q];
    }
#pragma unroll
    for(int k=0;k<4;k++){
      int s = k*512+t, jj = s>>4, q = s&15;
      *(float4*)(sB + (size_t)jj*SBST + q*4) = r[k];
    }
  }
  __syncthreads();

  const float* w2b = W2mp + phu*8;      // scalar (s_load) path
  const float4* aR0 = (const float4*)(sA + (2*ihu  )*Hn);
  const float4* aR1 = (const float4*)(sA + (2*ihu+1)*Hn);

  float acc0[8], acc1[8];
#pragma unroll
  for(int pp=0;pp<8;pp++){ acc0[pp]=0.f; acc1[pp]=0.f; }
  float dot0=0.f, dot1=0.f;

  for(int c=0; c<NCH; ++c){
    // ---- issue next-chunk global loads (consumed after this chunk's compute) ----
    float4 r[4];
    const bool more = (c+1 < NCH);
    if(more){
#pragma unroll
      for(int k=0;k<4;k++){
        int s = k*512+t, jj = s>>4, q = s&15;
        r[k] = ball[(size_t)jj*(Hn/4) + (c+1)*QCH + q];
      }
    }
    // ---- compute this chunk from LDS ----
    const float4* bb = (const float4*)(sB + (c&1)*SBUFSZ + (size_t)j*SBST);
#pragma unroll 2
    for(int hql=0; hql<QCH; ++hql){
      const int hq = c*QCH + hql;
      float4 a0 = aR0[hq];
      float4 a1 = aR1[hq];
      float4 bq = bb[hql];
#pragma unroll
      for(int d=0; d<4; ++d){
        float bv  = (d==0)? bq.x : (d==1)? bq.y : (d==2)? bq.z : bq.w;
        float a0v = (d==0)? a0.x : (d==1)? a0.y : (d==2)? a0.z : a0.w;
        float a1v = (d==0)? a1.x : (d==1)? a1.y : (d==2)? a1.z : a1.w;
        const float* wr = w2b + (size_t)(hq*4+d)*Pn;
        float pr0 = a0v*bv, pr1 = a1v*bv;
        dot0 += pr0; dot1 += pr1;
#pragma unroll
        for(int pp=0;pp<8;pp++){
          float wv = wr[pp];
          acc0[pp]=fmaf(wv,pr0,acc0[pp]);
          acc1[pp]=fmaf(wv,pr1,acc1[pp]);
        }
      }
    }
    __syncthreads();            // all reads of sB[(c+1)&1] (from chunk c-1) done
    if(more){
#pragma unroll
      for(int k=0;k<4;k++){
        int s = k*512+t, jj = s>>4, q = s&15;
        *(float4*)(sB + ((c+1)&1)*SBUFSZ + (size_t)jj*SBST + q*4) = r[k];
      }
      __syncthreads();          // sB[(c+1)&1] ready for next chunk's compute
    }
  }
  __syncthreads();              // sB dead; safe to alias sP/redR below

  const int iA = i0 + 2*ih, iB = iA+1;

  // ---- fused cosine write (ph==0 lanes own it) ----
  if(ph==0){
    float nj = fmaxf(n2[b*Ln+j], EPSF);
    cosM[((size_t)(b*Ln+iA))*Ln + j] = dot0/(fmaxf(n1[b*Ln+iA],EPSF)*nj);
    cosM[((size_t)(b*Ln+iB))*Ln + j] = dot1/(fmaxf(n1[b*Ln+iB],EPSF)*nj);
  }

  // ---- normalize e in place ----
#pragma unroll
  for(int pp=0;pp<8;pp++){
    float sl  = sqrtf(fmaxf(WN[wnIdx(1,2,b,ph*8+pp,j)],0.f));
    float sr0 = sqrtf(fmaxf(WN[wnIdx(0,2,b,ph*8+pp,iA)],0.f));
    float sr1 = sqrtf(fmaxf(WN[wnIdx(0,2,b,ph*8+pp,iB)],0.f));
    acc0[pp] = acc0[pp]/fmaxf(sr0*sl,EPSF);
    acc1[pp] = acc1[pp]/fmaxf(sr1*sl,EPSF);
  }

  // ---- side1 partials: mask over i-rows, combine ih-halves via LDS ----
  {
    float mr0 = m1[b*Ln+iA], mr1 = m1[b*Ln+iB];
    float pmax[8], psum[8];
#pragma unroll
    for(int pp=0;pp<8;pp++){
      float mx=NINF, sm=0.f;
      if(mr0!=0.f){ mx=acc0[pp]; sm=acc0[pp]; }
      if(mr1!=0.f){ mx=fmaxf(mx,acc1[pp]); sm+=acc1[pp]; }
      pmax[pp]=mx; psum[pp]=sm;
    }
    if(ih==0){
#pragma unroll
      for(int pp=0;pp<8;pp++){ sP[j][ph*8+pp][0]=pmax[pp]; sP[j][ph*8+pp][1]=psum[pp]; }
    }
    __syncthreads();
    if(ih==1){
#pragma unroll
      for(int pp=0;pp<8;pp++){
        float M = fmaxf(sP[j][ph*8+pp][0], pmax[pp]);
        float S = sP[j][ph*8+pp][1] + psum[pp];
        size_t o = ((((size_t)(b*Ln+j))*Pn + ph*8+pp)*32 + blockIdx.y)*2;
        part[o]=M; part[o+1]=S;
      }
    }
  }

  // ---- side0: reduce over j (mask2) ----
  {
    const bool valid = (m2[b*Ln+j]!=0.f);
    const int w = t>>6, l = t&63;
#pragma unroll
    for(int r=0;r<2;r++){
#pragma unroll
      for(int pp=0;pp<8;pp++){
        float m = r? acc1[pp] : acc0[pp];
        float vmax = valid? m : NINF;
        float vsum = valid? m : 0.f;
        vmax = wred_max(vmax);
        vsum = wred_sum(vsum);
        if(l==0){ redR[w][r][pp][0]=vmax; redR[w][r][pp][1]=vsum; }
      }
    }
    __syncthreads();
    if(t<128){
      int st=t&1, pp=(t>>1)&7, r=(t>>4)&1, phh=(t>>5)&1, ihh=t>>6;
      int wbase = 4*ihh + 2*phh;
      float A = redR[wbase][r][pp][st], Bv = redR[wbase+1][r][pp][st];
      int iL = 2*ihh + r, p = phh*8+pp;
      int len2 = min(max(lens[8+b],1),Ln);
      size_t o = ((size_t)(b*Ln + i0+iL))*Pn + p;      // side 0
      if(st==0) mvmax[o] = fmaxf(A,Bv);
      else      mvmean[o] = (A+Bv)/(float)len2;
    }
  }
}

// ---------------- k_mm2: combine side1 partials over 32 i-tiles ----------------
__global__ __launch_bounds__(256) void k_mm2(
    const float* __restrict__ part, const int* __restrict__ lens,
    float* __restrict__ mvmax, float* __restrict__ mvmean){
  int g = blockIdx.x*256 + threadIdx.x;   // 16384 = B*L*P
  int b = g>>11;
  const float4* q = (const float4*)(part + (size_t)g*64);
  float mx = NINF, sm = 0.f;
#pragma unroll
  for(int k=0;k<16;k++){
    float4 v = q[k];
    mx = fmaxf(mx, fmaxf(v.x, v.z));
    sm += v.y + v.w;
  }
  int len1 = min(max(lens[b],1),Ln);
  size_t o = (size_t)Bn*Ln*Pn + g;        // side 1 block of mv arrays
  mvmax[o] = mx;
  mvmean[o] = sm/(float)len1;
}

// ---------------- k_fin: attention + all 102 features; p-in-lane Phase B ----------------
// grid (16, Ln/2): x = side*8+b → XCD = b
__global__ __launch_bounds__(256) void k_fin(
    const float* __restrict__ c1f, const float* __restrict__ c2f,
    const float* __restrict__ cosM,
    const float* __restrict__ n1, const float* __restrict__ n2,
    const float* __restrict__ wn, const float* __restrict__ W2T,
    const float* __restrict__ mvmax, const float* __restrict__ mvmean,
    const int* __restrict__ lens,
    const float* __restrict__ m1, const float* __restrict__ m2,
    float* __restrict__ out){
  const int x = blockIdx.x, side = x>>3, b = x&7;
  const int r0 = blockIdx.y*2;
  const int t = threadIdx.x, w = t>>6, l = t&63;
  const float* selfF  = side? c2f : c1f;
  const float* otherF = side? c1f : c2f;
  const float* nSelf  = side? n2 : n1;
  const float* nOther = side? n1 : n2;
  const float* mInner = side? m1 : m2;
  const float* mSelfm = side? m2 : m1;
  int lenI = side? lens[b]    : lens[8+b];
  int lpO  = side? lens[16+b] : lens[24+b];
  lenI = min(max(lenI,1),Ln);
  lpO  = min(max(lpO,0),Ln-1);

  __shared__ float cS[2*Ln];
  __shared__ float mS[Ln];
  __shared__ float sV1[2][Hn];
  __shared__ float sF[Hn], sB[Hn];
  __shared__ float sAS[2][Hn], sAM[2][Hn];
  __shared__ float red[8][4];

  // ---- stage ----
  {
    if(side==0){
      const float* crow = cosM + ((size_t)(b*Ln+r0))*Ln;
      for(int idx=t; idx<2*Ln; idx+=256) cS[idx]=crow[idx];
    } else {
      int jj = t&127, rp = t>>7;   // transposed read: cos^T[r][j] = cosM[j][r]
      cS[rp*Ln+jj] = cosM[((size_t)(b*Ln+jj))*Ln + r0+rp];
    }
    if(t<Ln) mS[t]=mInner[b*Ln+t];
    const float4* s4 = (const float4*)(selfF + ((size_t)(b*Ln+r0))*Hn);
    float4* d4 = (float4*)sV1;
    for(int idx=t; idx<2*Hn/4; idx+=256) d4[idx]=s4[idx];
    const float4* f4 = (const float4*)(otherF + ((size_t)(b*Ln+lpO))*Hn);
    const float4* b4 = (const float4*)(otherF + ((size_t)(b*Ln))*Hn);
    if(t<Hn/4){ ((float4*)sF)[t]=f4[t]; ((float4*)sB)[t]=b4[t]; }
  }
  __syncthreads();

  // ---- attention accumulation (2 rows, h = 3t..3t+2) ----
  float aS0[3]={0,0,0}, aS1[3]={0,0,0}, aM0[3]={NINF,NINF,NINF}, aM1[3]={NINF,NINF,NINF};
  {
    const float* src = otherF + (size_t)b*Ln*Hn;
#pragma unroll 4
    for(int jj=0; jj<Ln; ++jj){
      float3 vk = ((const float3*)(src + (size_t)jj*Hn))[t];
      float msk = mS[jj];
      float c0=cS[jj], c1v=cS[Ln+jj];
      aS0[0]=fmaf(vk.x,c0 ,aS0[0]); aS0[1]=fmaf(vk.y,c0 ,aS0[1]); aS0[2]=fmaf(vk.z,c0 ,aS0[2]);
      aS1[0]=fmaf(vk.x,c1v,aS1[0]); aS1[1]=fmaf(vk.y,c1v,aS1[1]); aS1[2]=fmaf(vk.z,c1v,aS1[2]);
      if(msk!=0.f){
        aM0[0]=fmaxf(aM0[0],vk.x*c0 ); aM0[1]=fmaxf(aM0[1],vk.y*c0 ); aM0[2]=fmaxf(aM0[2],vk.z*c0 );
        aM1[0]=fmaxf(aM1[0],vk.x*c1v); aM1[1]=fmaxf(aM1[1],vk.y*c1v); aM1[2]=fmaxf(aM1[2],vk.z*c1v);
      }
    }
  }

  // ---- softmax over h (2 rows); -1e30 masking => fully-masked rows → uniform ----
  {
    float lm0 = fmaxf(fmaxf(aS0[0],aS0[1]),aS0[2]);
    float lm1 = fmaxf(fmaxf(aS1[0],aS1[1]),aS1[2]);
    lm0 = wred_max(lm0); lm1 = wred_max(lm1);
    if(l==0){ red[0][w]=lm0; red[1][w]=lm1; }
  }
  __syncthreads();
  float bm0 = fmaxf(fmaxf(red[0][0],red[0][1]),fmaxf(red[0][2],red[0][3]));
  float bm1 = fmaxf(fmaxf(red[1][0],red[1][1]),fmaxf(red[1][2],red[1][3]));
  __syncthreads();
  float ev0[3], ev1[3];
  {
    float es0=0.f, es1=0.f;
#pragma unroll
    for(int k=0;k<3;k++){
      ev0[k]=expf(aS0[k]-bm0); es0+=ev0[k];
      ev1[k]=expf(aS1[k]-bm1); es1+=ev1[k];
    }
    es0 = wred_sum(es0); es1 = wred_sum(es1);
    if(l==0){ red[0][w]=es0; red[1][w]=es1; }
  }
  __syncthreads();
  {
    float smr0 = mSelfm[b*Ln+r0], smr1 = mSelfm[b*Ln+r0+1];
    float bs0 = red[0][0]+red[0][1]+red[0][2]+red[0][3];
    float bs1 = red[1][0]+red[1][1]+red[1][2]+red[1][3];
    float inv0 = 1.f/fmaxf(bs0,EPSF), inv1 = 1.f/fmaxf(bs1,EPSF);
    const float u = 1.f/(float)Hn;
#pragma unroll
    for(int k=0;k<3;k++){
      sAS[0][3*t+k] = (smr0!=0.f)? ev0[k]*inv0 : u;
      sAS[1][3*t+k] = (smr1!=0.f)? ev1[k]*inv1 : u;
      sAM[0][3*t+k] = aM0[k];
      sAM[1][3*t+k] = aM1[k];
    }
  }
  __syncthreads();

  // ---- Phase A (waves 0-1) + Phase C (wave 2): independent, no barrier ----
  if(w<2){
    int rr = w;
    float cmx=NINF, csm=0.f;
    float ca = cS[rr*Ln + l], cb = cS[rr*Ln + l + 64];
    if(mS[l]!=0.f){ cmx=ca; csm=ca; }
    if(mS[l+64]!=0.f){ cmx=fmaxf(cmx,cb); csm+=cb; }
    cmx = wred_max(cmx); csm = wred_sum(csm);
    if(l==0){
      float* op = out + ((size_t)((b*2+side)*Ln + r0+rr))*Dn;
      op[0] = cmx;
      op[1] = csm/(float)lenI;
    }
  } else if(w==2){
    int rr = l>>5, qq = l&31, p = qq&15;
    size_t o = ((size_t)((side*Bn+b)*Ln + r0+rr))*Pn + p;
    float* op = out + ((size_t)((b*2+side)*Ln + r0+rr))*Dn;
    if(qq<16) op[36+p] = mvmax[o];
    else      op[52+p] = mvmean[o];
  }

  // ---- Phase B: wave w handles mi=w for both rows; lane = (p, hq) ----
  {
    const int Xids[4] = {0,1,3,4};
    const int offS[4] = {2,19,68,85};
    const int X = Xids[w], offs = offS[w];
    const bool dyn = (w>=2);
    const int p = l&15, hq = l>>4;
    const int h0 = hq*192;
    const float* w2p = W2T + ((size_t)X*Hn)*Pn + p;
    float acc0=0.f, acc1=0.f, s00=0.f, s01=0.f;
    float sn0=0.f, sn1=0.f, sna0=0.f, sna1=0.f;
    if(!dyn){
      const float* bvp = (w==0)? sF : sB;
#pragma unroll 4
      for(int hh=0; hh<192; ++hh){
        int h = h0+hh;
        float w2v = w2p[(size_t)h*Pn];
        float bv = bvp[h];
        float pr0 = sV1[0][h]*bv, pr1 = sV1[1][h]*bv;
        acc0 = fmaf(w2v,pr0,acc0); acc1 = fmaf(w2v,pr1,acc1);
        s00 += pr0; s01 += pr1;
      }
    } else {
      const float* bv0p = (w==2)? sAS[0] : sAM[0];
      const float* bv1p = (w==2)? sAS[1] : sAM[1];
#pragma unroll 4
      for(int hh=0; hh<192; ++hh){
        int h = h0+hh;
        float w2v = w2p[(size_t)h*Pn];
        float bv0 = bv0p[h], bv1 = bv1p[h];
        float pr0 = sV1[0][h]*bv0, pr1 = sV1[1][h]*bv1;
        float bb0 = bv0*bv0, bb1 = bv1*bv1;
        acc0 = fmaf(w2v,pr0,acc0); acc1 = fmaf(w2v,pr1,acc1);
        sna0 = fmaf(w2v,bb0,sna0); sna1 = fmaf(w2v,bb1,sna1);
        s00 += pr0; s01 += pr1;
        sn0 += bb0; sn1 += bb1;
      }
    }
    acc0 = qred_sum(acc0); acc1 = qred_sum(acc1);
    s00  = qred_sum(s00);  s01  = qred_sum(s01);
    if(dyn){
      sna0 = qred_sum(sna0); sna1 = qred_sum(sna1);
      sn0  = qred_sum(sn0);  sn1  = qred_sum(sn1);
    }
#pragma unroll
    for(int rr=0; rr<2; ++rr){
      const int r = r0+rr;
      float accv = rr? acc1 : acc0;
      float s0v  = rr? s01  : s00;
      float snav = rr? sna1 : sna0;
      float snv  = rr? sn1  : sn0;
      float* op = out + ((size_t)((b*2+side)*Ln + r))*Dn;
      if(l<16){
        float wa = fmaxf(wn[wnIdx(side,X,b,l,r)],0.f);
        float wb = dyn? fmaxf(snav,0.f)
                      : fmaxf(wn[wnIdx(1-side,X,b,l,(w==0? lpO:0))],0.f);
        float mul = accv/(fmaxf(sqrtf(wa),EPSF)*fmaxf(sqrtf(wb),EPSF));
        op[offs+1+l] = mul;
      }
      if(l==0){
        float nb = dyn? sqrtf(fmaxf(snv,0.f)) : nOther[b*Ln + (w==0? lpO : 0)];
        float nv1 = nSelf[b*Ln+r];
        op[offs] = s0v/(fmaxf(nv1,EPSF)*fmaxf(nb,EPSF));
      }
    }
  }
}

extern "C" void kernel_launch(void* const* d_in, const int* in_sizes, int n_in,
                              void* d_out, int out_size, void* d_ws, size_t ws_size,
                              hipStream_t stream) {
  const float* ctx1 = (const float*)d_in[0];
  const float* m1   = (const float*)d_in[1];
  const float* ctx2 = (const float*)d_in[2];
  const float* m2   = (const float*)d_in[3];
  const float* wff  = (const float*)d_in[4];
  const float* wfb  = (const float*)d_in[5];
  const float* wmp  = (const float*)d_in[6];
  const float* watt = (const float*)d_in[7];
  const float* wmatt= (const float*)d_in[8];
  float* out = (float*)d_out;
  float* W = (float*)d_ws;
  int* lens = (int*)(W + OFF_LENS);

  k_prep<<<dim3(8 + (5*Pn*Hn)/256), 256, 0, stream>>>(m1,m2,wff,wfb,wmp,watt,wmatt,
      W+OFF_W2T, lens);
  k_rows<<<dim3(Ln,Bn,2), 256, 0, stream>>>(ctx1,m1,ctx2,m2, W+OFF_W2T,
      W+OFF_C1F, W+OFF_C2F, W+OFF_N1, W+OFF_N2, W+OFF_WN);
  k_mm<<<dim3(Bn, Ln/4), 512, 0, stream>>>(W+OFF_C1F, W+OFF_C2F,
      W+OFF_W2T + (size_t)2*Hn*Pn, W+OFF_WN, W+OFF_N1, W+OFF_N2,
      m1, m2, lens, W+OFF_COS,
      W+OFF_MVMAX, W+OFF_MVMEAN, W+OFF_PART);
  k_mm2<<<dim3((Bn*Ln*Pn)/256), 256, 0, stream>>>(W+OFF_PART, lens,
      W+OFF_MVMAX, W+OFF_MVMEAN);
  k_fin<<<dim3(16, Ln/2), 256, 0, stream>>>(W+OFF_C1F, W+OFF_C2F, W+OFF_COS,
      W+OFF_N1, W+OFF_N2, W+OFF_WN, W+OFF_W2T, W+OFF_MVMAX, W+OFF_MVMEAN,
      lens, m1, m2, out);
}

// Round 5
// 243.837 us; speedup vs baseline: 1.1380x; 1.0591x over previous
//
#include <hip/hip_runtime.h>

#define Bn 8
#define Ln 128
#define Hn 768
#define Pn 16
#define Dn 102
#define EPSF 1e-8f
#define NINF -1e30f

__device__ __forceinline__ float wred_sum(float v){
#pragma unroll
  for(int o=32;o>=1;o>>=1) v += __shfl_xor(v,o);
  return v;
}
__device__ __forceinline__ float wred_max(float v){
#pragma unroll
  for(int o=32;o>=1;o>>=1) v = fmaxf(v,__shfl_xor(v,o));
  return v;
}
// sum over the 4 hq-quarters in the p-in-lane layout (lane = p + 16*hq)
__device__ __forceinline__ float qred_sum(float v){
  v += __shfl_xor(v,16);
  v += __shfl_xor(v,32);
  return v;
}

// ---- workspace layout (float element offsets; total ~12.7 MB) ----
constexpr size_t SZ_MAT   = (size_t)Bn*Ln*Hn;              // 786432
constexpr size_t OFF_C1F  = 0;
constexpr size_t OFF_C2F  = OFF_C1F + SZ_MAT;
constexpr size_t OFF_COS  = OFF_C2F + SZ_MAT;              // B*L*L
constexpr size_t OFF_N1   = OFF_COS + (size_t)Bn*Ln*Ln;    // B*L
constexpr size_t OFF_N2   = OFF_N1 + (size_t)Bn*Ln;
constexpr size_t OFF_WN   = OFF_N2 + (size_t)Bn*Ln;        // 2*5*B*P*L
constexpr size_t OFF_W2T  = OFF_WN + (size_t)2*5*Bn*Pn*Ln; // 5*H*P [X][h][p]
constexpr size_t OFF_MVMAX  = OFF_W2T + (size_t)5*Hn*Pn;   // 2*B*L*P
constexpr size_t OFF_MVMEAN = OFF_MVMAX + (size_t)2*Bn*Ln*Pn;
constexpr size_t OFF_PART   = OFF_MVMEAN + (size_t)2*Bn*Ln*Pn; // B*L*P*32*2 (side1)
constexpr size_t OFF_PART2  = OFF_PART + (size_t)Bn*Ln*Pn*32*2; // B*L*P*2*2 (side0 j-halves)
constexpr size_t OFF_LENS   = OFF_PART2 + (size_t)Bn*Ln*Pn*4;   // 32 ints

__device__ __forceinline__ size_t wnIdx(int side,int X,int b,int p,int i){
  return ((((size_t)side*5 + X)*Bn + b)*Pn + p)*Ln + i;
}

// ---------------- k_prep: lengths + squared-weight tables ----------------
__global__ __launch_bounds__(256) void k_prep(
    const float* __restrict__ m1, const float* __restrict__ m2,
    const float* __restrict__ wff, const float* __restrict__ wfb,
    const float* __restrict__ wmp, const float* __restrict__ watt,
    const float* __restrict__ wmatt,
    float* __restrict__ W2T, int* __restrict__ lens){
  int t = threadIdx.x;
  if(blockIdx.x < 8){
    int b = blockIdx.x;
    __shared__ int cnt[2];
    if(t<2) cnt[t]=0;
    __syncthreads();
    if(t<Ln){
      if(m1[b*Ln+t]>0.5f) atomicAdd(&cnt[0],1);
      if(m2[b*Ln+t]>0.5f) atomicAdd(&cnt[1],1);
    }
    __syncthreads();
    if(t==0){
      lens[b]=cnt[0]; lens[8+b]=cnt[1];
      lens[16+b]=max(cnt[0]-1,0); lens[24+b]=max(cnt[1]-1,0);
    }
  } else {
    int idx = (blockIdx.x-8)*256 + t;     // < 5*768*16 = 61440
    const float* srcs[5] = {wff,wfb,wmp,watt,wmatt};
    int X = idx/(Pn*Hn);
    int r = idx%(Pn*Hn);
    int h = r/Pn, p = r%Pn;
    float w = srcs[X][p*Hn+h];
    W2T[idx] = w*w;                        // layout [X][h][p]
  }
}

// ---------------- k_rows: masked rows + norms + weighted norms ----------------
__global__ __launch_bounds__(256) void k_rows(
    const float* __restrict__ ctx1, const float* __restrict__ m1,
    const float* __restrict__ ctx2, const float* __restrict__ m2,
    const float* __restrict__ W2T,
    float* __restrict__ c1f, float* __restrict__ c2f,
    float* __restrict__ n1, float* __restrict__ n2, float* __restrict__ wn){
  int i = blockIdx.x, b = blockIdx.y, side = blockIdx.z;
  const float* ctx = side? ctx2 : ctx1;
  const float* msk = side? m2 : m1;
  float* dst = side? c2f : c1f;
  float* nD  = side? n2 : n1;
  int t = threadIdx.x, w=t>>6, l=t&63;
  float mk = msk[b*Ln+i];
  size_t base = ((size_t)(b*Ln+i))*Hn;
  float v[3];
#pragma unroll
  for(int k=0;k<3;k++){
    float x = ctx[base + t + 256*k] * mk;
    v[k]=x;
    dst[base + t + 256*k] = x;
  }
  __shared__ float red4[4];
  __shared__ float redW[64];
  float ss = v[0]*v[0]+v[1]*v[1]+v[2]*v[2];
  float sst = wred_sum(ss);
  if(l==0) red4[w]=sst;
  __syncthreads();
  if(t==0) nD[b*Ln+i] = sqrtf(fmaxf(red4[0]+red4[1]+red4[2]+red4[3],0.f));
  for(int X=0;X<5;++X){
    float acc[16];
#pragma unroll
    for(int p=0;p<16;p++) acc[p]=0.f;
#pragma unroll
    for(int k=0;k<3;k++){
      int h = t+256*k;
      float vv = v[k]*v[k];
      const float4* wq = (const float4*)(W2T + ((size_t)X*Hn + h)*Pn);
      float4 q0=wq[0],q1=wq[1],q2=wq[2],q3=wq[3];
      float wv[16]={q0.x,q0.y,q0.z,q0.w,q1.x,q1.y,q1.z,q1.w,
                    q2.x,q2.y,q2.z,q2.w,q3.x,q3.y,q3.z,q3.w};
#pragma unroll
      for(int p=0;p<16;p++) acc[p]=fmaf(wv[p],vv,acc[p]);
    }
    __syncthreads();
#pragma unroll
    for(int p=0;p<16;p++){
      float a = wred_sum(acc[p]);
      if(l==0) redW[w*16+p]=a;
    }
    __syncthreads();
    if(t<16){
      float s = redW[t]+redW[16+t]+redW[32+t]+redW[48+t];
      wn[wnIdx(side,X,b,t,i)] = s;
    }
    __syncthreads();
  }
}

// ---------------- k_mm: e-tensor + fused cos ----------------
// grid (Bn, 64): y = itile*2 + jh → 512 blocks = 2 blocks/CU (16 waves/CU).
// 512 thr = (jl:64, ph:2, row:4); thread = 1 i-row × 8 p for its j = jh*64+jl.
// Lessons encoded:
//  R0/R2: per-hq lgkm drain (ds+SMEM share counter) exposed ~200cy/hq at 2 waves/SIMD.
//  R1/R3: scattered brow (64 lines/wave-load) is a shared TA-throughput wall — more
//         waves made it WORSE. Fix: coalesced chunked staging of B.
//  R4:    staging regs held across 2 barriers spilled to scratch (+8MB HBM writes).
//         Fix: only 2 float4 in flight, ONE barrier/chunk, 2-deep buffer.
//  LDS:   linear [64][64] + XOR swizzle (q ^= r&15) on write AND read → ds_write/
//         ds_read_b128 both at the uniform data-path floor (no 16-way conflicts,
//         no pad → 16B alignment kept).
#define HC 64                  // h per chunk
#define NCH (Hn/HC)            // 12 chunks
#define QCH (HC/4)             // 16 float4 per row per chunk
#define BUFQ (64*64)           // floats per buffer (16 KB)

__global__ __launch_bounds__(512) void k_mm(
    const float* __restrict__ c1f, const float* __restrict__ c2f,
    const float* __restrict__ W2mp, const float* __restrict__ WN,
    const float* __restrict__ n1, const float* __restrict__ n2,
    const float* __restrict__ m1, const float* __restrict__ m2,
    float* __restrict__ cosM,
    float* __restrict__ part, float* __restrict__ part2){
  const int b = blockIdx.x;
  const int itile = blockIdx.y >> 1;       // 0..31
  const int jh = blockIdx.y & 1;           // j-half
  const int i0 = itile*4;
  const int t = threadIdx.x;
  const int jl = t & 63;
  const int ph = (t>>6) & 1;
  const int row = t>>7;                    // 0..3
  const int j  = jh*64 + jl;
  const int phu  = __builtin_amdgcn_readfirstlane(ph);
  const int rowu = __builtin_amdgcn_readfirstlane(row);

  // LDS pool: sA (12KB) + sB 2 bufs (32KB) = 44KB → 2 blocks/CU.
  // sP2 (side1 combine, 32KB) aliases sB post-loop (barrier-separated).
  __shared__ __align__(16) float pool[3072 + 2*BUFQ];
  float* sA = pool;                        // [4][768]
  float* sB = pool + 3072;                 // [2][64][64] swizzled
  float* sP2 = pool + 3072;                // alias: [4][64][16][2]

  const float4* gball = (const float4*)(c2f + (size_t)b*Ln*Hn);
  const int sr0 = t>>4, sq = t&15;         // staging decomposition
  const int swz0 = (sq ^ (sr0&15))<<2;     // same for row sr0 and sr0+32

  // ---- prologue: stage A-rows + chunk 0 of B ----
  {
    const float4* arow4 = (const float4*)(c1f + ((size_t)(b*Ln+i0))*Hn);
    float4* sA4 = (float4*)sA;
    for(int idx=t; idx<Hn; idx+=512) sA4[idx] = arow4[idx];  // 4 rows = 768 float4
    float4 v0 = gball[(size_t)(jh*64 + sr0     )*(Hn/4) + sq];
    float4 v1 = gball[(size_t)(jh*64 + sr0 + 32)*(Hn/4) + sq];
    *(float4*)(sB + (size_t)sr0*64      + swz0) = v0;
    *(float4*)(sB + (size_t)(sr0+32)*64 + swz0) = v1;
  }
  __syncthreads();

  const float* w2b = W2mp + phu*8;      // scalar (s_load) path
  const float4* aR = (const float4*)(sA + rowu*Hn);
  const int jx = jl & 15;
  const float* sBrow = sB + (size_t)jl*64;

  float acc[8];
#pragma unroll
  for(int pp=0;pp<8;pp++) acc[pp]=0.f;
  float dot=0.f;

  for(int c=0; c<NCH; ++c){
    // ---- issue next-chunk global loads (2 float4 in flight; consumed post-compute) ----
    float4 v0, v1;
    const bool more = (c+1 < NCH);
    if(more){
      v0 = gball[(size_t)(jh*64 + sr0     )*(Hn/4) + (c+1)*QCH + sq];
      v1 = gball[(size_t)(jh*64 + sr0 + 32)*(Hn/4) + (c+1)*QCH + sq];
    }
    // ---- compute this chunk from swizzled LDS ----
    const float* bbuf = sBrow + (c&1)*BUFQ;
#pragma unroll 2
    for(int hql=0; hql<QCH; ++hql){
      const int hq = c*QCH + hql;
      float4 a  = aR[hq];                                   // wave-uniform broadcast
      float4 bq = *(const float4*)(bbuf + ((hql ^ jx)<<2)); // swizzled read
#pragma unroll
      for(int d=0; d<4; ++d){
        float bv = (d==0)? bq.x : (d==1)? bq.y : (d==2)? bq.z : bq.w;
        float av = (d==0)? a.x  : (d==1)? a.y  : (d==2)? a.z  : a.w;
        const float* wr = w2b + (size_t)(hq*4+d)*Pn;
        float pr = av*bv;
        dot += pr;
#pragma unroll
        for(int pp=0;pp<8;pp++) acc[pp]=fmaf(wr[pp],pr,acc[pp]);
      }
    }
    if(more){
      // write buf[(c+1)&1]: its last readers (chunk c-1) finished at the previous
      // barrier; current readers use buf[c&1]. One barrier per chunk.
      *(float4*)(sB + ((c+1)&1)*BUFQ + (size_t)sr0*64      + swz0) = v0;
      *(float4*)(sB + ((c+1)&1)*BUFQ + (size_t)(sr0+32)*64 + swz0) = v1;
      __syncthreads();
    }
  }
  __syncthreads();              // last compute done; sB free → alias sP2

  const int iR = i0 + row;

  // ---- fused cosine write (ph==0 threads own it) ----
  if(ph==0){
    float nj = fmaxf(n2[b*Ln+j], EPSF);
    cosM[((size_t)(b*Ln+iR))*Ln + j] = dot/(fmaxf(n1[b*Ln+iR],EPSF)*nj);
  }

  // ---- normalize e in place ----
#pragma unroll
  for(int pp=0;pp<8;pp++){
    int p = ph*8+pp;
    float sl = sqrtf(fmaxf(WN[wnIdx(1,2,b,p,j)],0.f));
    float sr = sqrtf(fmaxf(WN[wnIdx(0,2,b,p,iR)],0.f));
    acc[pp] = acc[pp]/fmaxf(sr*sl,EPSF);
  }

  // ---- side0 partial: in-wave reduce over 64 jl (mask2); lanes ARE jl ----
  {
    const bool valid = (m2[b*Ln+j]!=0.f);
#pragma unroll
    for(int pp=0;pp<8;pp++){
      float vmax = valid? acc[pp] : NINF;
      float vsum = valid? acc[pp] : 0.f;
      vmax = wred_max(vmax);
      vsum = wred_sum(vsum);
      if(jl==0){
        size_t o = (((size_t)(b*Ln+iR))*Pn + ph*8+pp)*4 + jh*2;
        part2[o]   = vmax;
        part2[o+1] = vsum;
      }
    }
  }

  // ---- side1 partial: masked per-row values → aliased LDS → combine over 4 rows ----
  {
    float mr = m1[b*Ln+iR];
#pragma unroll
    for(int pp=0;pp<8;pp++){
      int p = ph*8+pp;
      size_t o = ((size_t)((row*64 + jl)*16 + p))*2;
      sP2[o]   = (mr!=0.f)? acc[pp] : NINF;
      sP2[o+1] = (mr!=0.f)? acc[pp] : 0.f;
    }
  }
  __syncthreads();
  for(int it=t; it<64*16; it+=512){
    int jl2 = it>>4, p2 = it&15;
    float M=NINF, S=0.f;
#pragma unroll
    for(int r=0;r<4;r++){
      size_t o = ((size_t)((r*64+jl2)*16 + p2))*2;
      M = fmaxf(M, sP2[o]);
      S += sP2[o+1];
    }
    int j2 = jh*64 + jl2;
    size_t o = ((((size_t)(b*Ln+j2))*Pn + p2)*32 + itile)*2;
    part[o]=M; part[o+1]=S;
  }
}

// ---------------- k_mm2: combine side1 partials (32 i-tiles) + side0 (2 j-halves) ----------------
__global__ __launch_bounds__(256) void k_mm2(
    const float* __restrict__ part, const float* __restrict__ part2,
    const int* __restrict__ lens,
    float* __restrict__ mvmax, float* __restrict__ mvmean){
  int g = blockIdx.x*256 + threadIdx.x;   // 16384 = B*L*P
  int b = g>>11;
  // side 1: over 32 i-tiles
  const float4* q = (const float4*)(part + (size_t)g*64);
  float mx = NINF, sm = 0.f;
#pragma unroll
  for(int k=0;k<16;k++){
    float4 v = q[k];
    mx = fmaxf(mx, fmaxf(v.x, v.z));
    sm += v.y + v.w;
  }
  int len1 = min(max(lens[b],1),Ln);
  size_t o1 = (size_t)Bn*Ln*Pn + g;       // side 1 block of mv arrays
  mvmax[o1] = mx;
  mvmean[o1] = sm/(float)len1;
  // side 0: over 2 j-halves
  float4 v2 = *(const float4*)(part2 + (size_t)g*4);
  int len2 = min(max(lens[8+b],1),Ln);
  mvmax[g]  = fmaxf(v2.x, v2.z);
  mvmean[g] = (v2.y + v2.w)/(float)len2;
}

// ---------------- k_fin: attention + all 102 features; p-in-lane Phase B ----------------
// grid (16, Ln/2): x = side*8+b → XCD = b
__global__ __launch_bounds__(256) void k_fin(
    const float* __restrict__ c1f, const float* __restrict__ c2f,
    const float* __restrict__ cosM,
    const float* __restrict__ n1, const float* __restrict__ n2,
    const float* __restrict__ wn, const float* __restrict__ W2T,
    const float* __restrict__ mvmax, const float* __restrict__ mvmean,
    const int* __restrict__ lens,
    const float* __restrict__ m1, const float* __restrict__ m2,
    float* __restrict__ out){
  const int x = blockIdx.x, side = x>>3, b = x&7;
  const int r0 = blockIdx.y*2;
  const int t = threadIdx.x, w = t>>6, l = t&63;
  const float* selfF  = side? c2f : c1f;
  const float* otherF = side? c1f : c2f;
  const float* nSelf  = side? n2 : n1;
  const float* nOther = side? n1 : n2;
  const float* mInner = side? m1 : m2;
  const float* mSelfm = side? m2 : m1;
  int lenI = side? lens[b]    : lens[8+b];
  int lpO  = side? lens[16+b] : lens[24+b];
  lenI = min(max(lenI,1),Ln);
  lpO  = min(max(lpO,0),Ln-1);

  __shared__ float cS[2*Ln];
  __shared__ float mS[Ln];
  __shared__ float sV1[2][Hn];
  __shared__ float sF[Hn], sB[Hn];
  __shared__ float sAS[2][Hn], sAM[2][Hn];
  __shared__ float red[8][4];

  // ---- stage ----
  {
    if(side==0){
      const float* crow = cosM + ((size_t)(b*Ln+r0))*Ln;
      for(int idx=t; idx<2*Ln; idx+=256) cS[idx]=crow[idx];
    } else {
      int jj = t&127, rp = t>>7;   // transposed read: cos^T[r][j] = cosM[j][r]
      cS[rp*Ln+jj] = cosM[((size_t)(b*Ln+jj))*Ln + r0+rp];
    }
    if(t<Ln) mS[t]=mInner[b*Ln+t];
    const float4* s4 = (const float4*)(selfF + ((size_t)(b*Ln+r0))*Hn);
    float4* d4 = (float4*)sV1;
    for(int idx=t; idx<2*Hn/4; idx+=256) d4[idx]=s4[idx];
    const float4* f4 = (const float4*)(otherF + ((size_t)(b*Ln+lpO))*Hn);
    const float4* b4 = (const float4*)(otherF + ((size_t)(b*Ln))*Hn);
    if(t<Hn/4){ ((float4*)sF)[t]=f4[t]; ((float4*)sB)[t]=b4[t]; }
  }
  __syncthreads();

  // ---- attention accumulation (2 rows, h = 3t..3t+2) ----
  float aS0[3]={0,0,0}, aS1[3]={0,0,0}, aM0[3]={NINF,NINF,NINF}, aM1[3]={NINF,NINF,NINF};
  {
    const float* src = otherF + (size_t)b*Ln*Hn;
#pragma unroll 4
    for(int jj=0; jj<Ln; ++jj){
      float3 vk = ((const float3*)(src + (size_t)jj*Hn))[t];
      float msk = mS[jj];
      float c0=cS[jj], c1v=cS[Ln+jj];
      aS0[0]=fmaf(vk.x,c0 ,aS0[0]); aS0[1]=fmaf(vk.y,c0 ,aS0[1]); aS0[2]=fmaf(vk.z,c0 ,aS0[2]);
      aS1[0]=fmaf(vk.x,c1v,aS1[0]); aS1[1]=fmaf(vk.y,c1v,aS1[1]); aS1[2]=fmaf(vk.z,c1v,aS1[2]);
      if(msk!=0.f){
        aM0[0]=fmaxf(aM0[0],vk.x*c0 ); aM0[1]=fmaxf(aM0[1],vk.y*c0 ); aM0[2]=fmaxf(aM0[2],vk.z*c0 );
        aM1[0]=fmaxf(aM1[0],vk.x*c1v); aM1[1]=fmaxf(aM1[1],vk.y*c1v); aM1[2]=fmaxf(aM1[2],vk.z*c1v);
      }
    }
  }

  // ---- softmax over h (2 rows); -1e30 masking => fully-masked rows → uniform ----
  {
    float lm0 = fmaxf(fmaxf(aS0[0],aS0[1]),aS0[2]);
    float lm1 = fmaxf(fmaxf(aS1[0],aS1[1]),aS1[2]);
    lm0 = wred_max(lm0); lm1 = wred_max(lm1);
    if(l==0){ red[0][w]=lm0; red[1][w]=lm1; }
  }
  __syncthreads();
  float bm0 = fmaxf(fmaxf(red[0][0],red[0][1]),fmaxf(red[0][2],red[0][3]));
  float bm1 = fmaxf(fmaxf(red[1][0],red[1][1]),fmaxf(red[1][2],red[1][3]));
  __syncthreads();
  float ev0[3], ev1[3];
  {
    float es0=0.f, es1=0.f;
#pragma unroll
    for(int k=0;k<3;k++){
      ev0[k]=expf(aS0[k]-bm0); es0+=ev0[k];
      ev1[k]=expf(aS1[k]-bm1); es1+=ev1[k];
    }
    es0 = wred_sum(es0); es1 = wred_sum(es1);
    if(l==0){ red[0][w]=es0; red[1][w]=es1; }
  }
  __syncthreads();
  {
    float smr0 = mSelfm[b*Ln+r0], smr1 = mSelfm[b*Ln+r0+1];
    float bs0 = red[0][0]+red[0][1]+red[0][2]+red[0][3];
    float bs1 = red[1][0]+red[1][1]+red[1][2]+red[1][3];
    float inv0 = 1.f/fmaxf(bs0,EPSF), inv1 = 1.f/fmaxf(bs1,EPSF);
    const float u = 1.f/(float)Hn;
#pragma unroll
    for(int k=0;k<3;k++){
      sAS[0][3*t+k] = (smr0!=0.f)? ev0[k]*inv0 : u;
      sAS[1][3*t+k] = (smr1!=0.f)? ev1[k]*inv1 : u;
      sAM[0][3*t+k] = aM0[k];
      sAM[1][3*t+k] = aM1[k];
    }
  }
  __syncthreads();

  // ---- Phase A (waves 0-1) + Phase C (wave 2): independent, no barrier ----
  if(w<2){
    int rr = w;
    float cmx=NINF, csm=0.f;
    float ca = cS[rr*Ln + l], cb = cS[rr*Ln + l + 64];
    if(mS[l]!=0.f){ cmx=ca; csm=ca; }
    if(mS[l+64]!=0.f){ cmx=fmaxf(cmx,cb); csm+=cb; }
    cmx = wred_max(cmx); csm = wred_sum(csm);
    if(l==0){
      float* op = out + ((size_t)((b*2+side)*Ln + r0+rr))*Dn;
      op[0] = cmx;
      op[1] = csm/(float)lenI;
    }
  } else if(w==2){
    int rr = l>>5, qq = l&31, p = qq&15;
    size_t o = ((size_t)((side*Bn+b)*Ln + r0+rr))*Pn + p;
    float* op = out + ((size_t)((b*2+side)*Ln + r0+rr))*Dn;
    if(qq<16) op[36+p] = mvmax[o];
    else      op[52+p] = mvmean[o];
  }

  // ---- Phase B: wave w handles mi=w for both rows; lane = (p, hq) ----
  {
    const int Xids[4] = {0,1,3,4};
    const int offS[4] = {2,19,68,85};
    const int X = Xids[w], offs = offS[w];
    const bool dyn = (w>=2);
    const int p = l&15, hq = l>>4;
    const int h0 = hq*192;
    const float* w2p = W2T + ((size_t)X*Hn)*Pn + p;
    float acc0=0.f, acc1=0.f, s00=0.f, s01=0.f;
    float sn0=0.f, sn1=0.f, sna0=0.f, sna1=0.f;
    if(!dyn){
      const float* bvp = (w==0)? sF : sB;
#pragma unroll 4
      for(int hh=0; hh<192; ++hh){
        int h = h0+hh;
        float w2v = w2p[(size_t)h*Pn];
        float bv = bvp[h];
        float pr0 = sV1[0][h]*bv, pr1 = sV1[1][h]*bv;
        acc0 = fmaf(w2v,pr0,acc0); acc1 = fmaf(w2v,pr1,acc1);
        s00 += pr0; s01 += pr1;
      }
    } else {
      const float* bv0p = (w==2)? sAS[0] : sAM[0];
      const float* bv1p = (w==2)? sAS[1] : sAM[1];
#pragma unroll 4
      for(int hh=0; hh<192; ++hh){
        int h = h0+hh;
        float w2v = w2p[(size_t)h*Pn];
        float bv0 = bv0p[h], bv1 = bv1p[h];
        float pr0 = sV1[0][h]*bv0, pr1 = sV1[1][h]*bv1;
        float bb0 = bv0*bv0, bb1 = bv1*bv1;
        acc0 = fmaf(w2v,pr0,acc0); acc1 = fmaf(w2v,pr1,acc1);
        sna0 = fmaf(w2v,bb0,sna0); sna1 = fmaf(w2v,bb1,sna1);
        s00 += pr0; s01 += pr1;
        sn0 += bb0; sn1 += bb1;
      }
    }
    acc0 = qred_sum(acc0); acc1 = qred_sum(acc1);
    s00  = qred_sum(s00);  s01  = qred_sum(s01);
    if(dyn){
      sna0 = qred_sum(sna0); sna1 = qred_sum(sna1);
      sn0  = qred_sum(sn0);  sn1  = qred_sum(sn1);
    }
#pragma unroll
    for(int rr=0; rr<2; ++rr){
      const int r = r0+rr;
      float accv = rr? acc1 : acc0;
      float s0v  = rr? s01  : s00;
      float snav = rr? sna1 : sna0;
      float snv  = rr? sn1  : sn0;
      float* op = out + ((size_t)((b*2+side)*Ln + r))*Dn;
      if(l<16){
        float wa = fmaxf(wn[wnIdx(side,X,b,l,r)],0.f);
        float wb = dyn? fmaxf(snav,0.f)
                      : fmaxf(wn[wnIdx(1-side,X,b,l,(w==0? lpO:0))],0.f);
        float mul = accv/(fmaxf(sqrtf(wa),EPSF)*fmaxf(sqrtf(wb),EPSF));
        op[offs+1+l] = mul;
      }
      if(l==0){
        float nb = dyn? sqrtf(fmaxf(snv,0.f)) : nOther[b*Ln + (w==0? lpO : 0)];
        float nv1 = nSelf[b*Ln+r];
        op[offs] = s0v/(fmaxf(nv1,EPSF)*fmaxf(nb,EPSF));
      }
    }
  }
}

extern "C" void kernel_launch(void* const* d_in, const int* in_sizes, int n_in,
                              void* d_out, int out_size, void* d_ws, size_t ws_size,
                              hipStream_t stream) {
  const float* ctx1 = (const float*)d_in[0];
  const float* m1   = (const float*)d_in[1];
  const float* ctx2 = (const float*)d_in[2];
  const float* m2   = (const float*)d_in[3];
  const float* wff  = (const float*)d_in[4];
  const float* wfb  = (const float*)d_in[5];
  const float* wmp  = (const float*)d_in[6];
  const float* watt = (const float*)d_in[7];
  const float* wmatt= (const float*)d_in[8];
  float* out = (float*)d_out;
  float* W = (float*)d_ws;
  int* lens = (int*)(W + OFF_LENS);

  k_prep<<<dim3(8 + (5*Pn*Hn)/256), 256, 0, stream>>>(m1,m2,wff,wfb,wmp,watt,wmatt,
      W+OFF_W2T, lens);
  k_rows<<<dim3(Ln,Bn,2), 256, 0, stream>>>(ctx1,m1,ctx2,m2, W+OFF_W2T,
      W+OFF_C1F, W+OFF_C2F, W+OFF_N1, W+OFF_N2, W+OFF_WN);
  k_mm<<<dim3(Bn, 64), 512, 0, stream>>>(W+OFF_C1F, W+OFF_C2F,
      W+OFF_W2T + (size_t)2*Hn*Pn, W+OFF_WN, W+OFF_N1, W+OFF_N2,
      m1, m2, W+OFF_COS, W+OFF_PART, W+OFF_PART2);
  k_mm2<<<dim3((Bn*Ln*Pn)/256), 256, 0, stream>>>(W+OFF_PART, W+OFF_PART2, lens,
      W+OFF_MVMAX, W+OFF_MVMEAN);
  k_fin<<<dim3(16, Ln/2), 256, 0, stream>>>(W+OFF_C1F, W+OFF_C2F, W+OFF_COS,
      W+OFF_N1, W+OFF_N2, W+OFF_WN, W+OFF_W2T, W+OFF_MVMAX, W+OFF_MVMEAN,
      lens, m1, m2, out);
}

// Round 6
// 242.915 us; speedup vs baseline: 1.1423x; 1.0038x over previous
//
#include <hip/hip_runtime.h>

#define Bn 8
#define Ln 128
#define Hn 768
#define Pn 16
#define Dn 102
#define EPSF 1e-8f
#define NINF -1e30f

__device__ __forceinline__ float wred_sum(float v){
#pragma unroll
  for(int o=32;o>=1;o>>=1) v += __shfl_xor(v,o);
  return v;
}
__device__ __forceinline__ float wred_max(float v){
#pragma unroll
  for(int o=32;o>=1;o>>=1) v = fmaxf(v,__shfl_xor(v,o));
  return v;
}
// sum over the 4 hq-quarters in the p-in-lane layout (lane = p + 16*hq)
__device__ __forceinline__ float qred_sum(float v){
  v += __shfl_xor(v,16);
  v += __shfl_xor(v,32);
  return v;
}

// ---- workspace layout (float element offsets; total ~12.7 MB) ----
constexpr size_t SZ_MAT   = (size_t)Bn*Ln*Hn;              // 786432
constexpr size_t OFF_C1F  = 0;
constexpr size_t OFF_C2F  = OFF_C1F + SZ_MAT;
constexpr size_t OFF_COS  = OFF_C2F + SZ_MAT;              // B*L*L
constexpr size_t OFF_N1   = OFF_COS + (size_t)Bn*Ln*Ln;    // B*L
constexpr size_t OFF_N2   = OFF_N1 + (size_t)Bn*Ln;
constexpr size_t OFF_WN   = OFF_N2 + (size_t)Bn*Ln;        // 2*5*B*P*L
constexpr size_t OFF_W2T  = OFF_WN + (size_t)2*5*Bn*Pn*Ln; // 5*H*P [X][h][p]
constexpr size_t OFF_MVMAX  = OFF_W2T + (size_t)5*Hn*Pn;   // 2*B*L*P
constexpr size_t OFF_MVMEAN = OFF_MVMAX + (size_t)2*Bn*Ln*Pn;
constexpr size_t OFF_PART   = OFF_MVMEAN + (size_t)2*Bn*Ln*Pn; // B*L*P*32*2 (side1)
constexpr size_t OFF_PART2  = OFF_PART + (size_t)Bn*Ln*Pn*32*2; // B*L*P*2*2 (side0 j-halves)
constexpr size_t OFF_LENS   = OFF_PART2 + (size_t)Bn*Ln*Pn*4;   // 32 ints

__device__ __forceinline__ size_t wnIdx(int side,int X,int b,int p,int i){
  return ((((size_t)side*5 + X)*Bn + b)*Pn + p)*Ln + i;
}

// ---------------- k_prep: lengths + squared-weight tables ----------------
__global__ __launch_bounds__(256) void k_prep(
    const float* __restrict__ m1, const float* __restrict__ m2,
    const float* __restrict__ wff, const float* __restrict__ wfb,
    const float* __restrict__ wmp, const float* __restrict__ watt,
    const float* __restrict__ wmatt,
    float* __restrict__ W2T, int* __restrict__ lens){
  int t = threadIdx.x;
  if(blockIdx.x < 8){
    int b = blockIdx.x;
    __shared__ int cnt[2];
    if(t<2) cnt[t]=0;
    __syncthreads();
    if(t<Ln){
      if(m1[b*Ln+t]>0.5f) atomicAdd(&cnt[0],1);
      if(m2[b*Ln+t]>0.5f) atomicAdd(&cnt[1],1);
    }
    __syncthreads();
    if(t==0){
      lens[b]=cnt[0]; lens[8+b]=cnt[1];
      lens[16+b]=max(cnt[0]-1,0); lens[24+b]=max(cnt[1]-1,0);
    }
  } else {
    int idx = (blockIdx.x-8)*256 + t;     // < 5*768*16 = 61440
    const float* srcs[5] = {wff,wfb,wmp,watt,wmatt};
    int X = idx/(Pn*Hn);
    int r = idx%(Pn*Hn);
    int h = r/Pn, p = r%Pn;
    float w = srcs[X][p*Hn+h];
    W2T[idx] = w*w;                        // layout [X][h][p]
  }
}

// ---------------- k_rows: masked rows + norms + weighted norms ----------------
__global__ __launch_bounds__(256) void k_rows(
    const float* __restrict__ ctx1, const float* __restrict__ m1,
    const float* __restrict__ ctx2, const float* __restrict__ m2,
    const float* __restrict__ W2T,
    float* __restrict__ c1f, float* __restrict__ c2f,
    float* __restrict__ n1, float* __restrict__ n2, float* __restrict__ wn){
  int i = blockIdx.x, b = blockIdx.y, side = blockIdx.z;
  const float* ctx = side? ctx2 : ctx1;
  const float* msk = side? m2 : m1;
  float* dst = side? c2f : c1f;
  float* nD  = side? n2 : n1;
  int t = threadIdx.x, w=t>>6, l=t&63;
  float mk = msk[b*Ln+i];
  size_t base = ((size_t)(b*Ln+i))*Hn;
  float v[3];
#pragma unroll
  for(int k=0;k<3;k++){
    float x = ctx[base + t + 256*k] * mk;
    v[k]=x;
    dst[base + t + 256*k] = x;
  }
  __shared__ float red4[4];
  __shared__ float redW[64];
  float ss = v[0]*v[0]+v[1]*v[1]+v[2]*v[2];
  float sst = wred_sum(ss);
  if(l==0) red4[w]=sst;
  __syncthreads();
  if(t==0) nD[b*Ln+i] = sqrtf(fmaxf(red4[0]+red4[1]+red4[2]+red4[3],0.f));
  for(int X=0;X<5;++X){
    float acc[16];
#pragma unroll
    for(int p=0;p<16;p++) acc[p]=0.f;
#pragma unroll
    for(int k=0;k<3;k++){
      int h = t+256*k;
      float vv = v[k]*v[k];
      const float4* wq = (const float4*)(W2T + ((size_t)X*Hn + h)*Pn);
      float4 q0=wq[0],q1=wq[1],q2=wq[2],q3=wq[3];
      float wv[16]={q0.x,q0.y,q0.z,q0.w,q1.x,q1.y,q1.z,q1.w,
                    q2.x,q2.y,q2.z,q2.w,q3.x,q3.y,q3.z,q3.w};
#pragma unroll
      for(int p=0;p<16;p++) acc[p]=fmaf(wv[p],vv,acc[p]);
    }
    __syncthreads();
#pragma unroll
    for(int p=0;p<16;p++){
      float a = wred_sum(acc[p]);
      if(l==0) redW[w*16+p]=a;
    }
    __syncthreads();
    if(t<16){
      float s = redW[t]+redW[16+t]+redW[32+t]+redW[48+t];
      wn[wnIdx(side,X,b,t,i)] = s;
    }
    __syncthreads();
  }
}

// ---------------- k_mm: e-tensor + fused cos ----------------
// grid (Bn, 64): y = itile*2 + jh → 512 blocks = 2 blocks/CU (16 waves/CU).
// 512 thr = (jl:64, ph:2, row:4); thread = 1 i-row × 8 p for its j = jh*64+jl.
// Lessons encoded:
//  R0/R2: per-hq lgkm drain (ds+SMEM share counter) exposed ~200cy/hq at 2 waves/SIMD.
//  R1/R3: scattered brow (64 lines/wave-load) is a shared TA-throughput wall — more
//         waves made it WORSE. Fix: coalesced chunked staging of B.
//  R4:    staging regs held across 2 barriers spilled to scratch (+8MB HBM writes).
//         Fix: only 2 float4 in flight, ONE barrier/chunk, 2-deep buffer.
//  LDS:   linear [64][64] + XOR swizzle (q ^= r&15) on write AND read → ds_write/
//         ds_read_b128 both at the uniform data-path floor (no 16-way conflicts,
//         no pad → 16B alignment kept).
#define HC 64                  // h per chunk
#define NCH (Hn/HC)            // 12 chunks
#define QCH (HC/4)             // 16 float4 per row per chunk
#define BUFQ (64*64)           // floats per buffer (16 KB)

__global__ __launch_bounds__(512) void k_mm(
    const float* __restrict__ c1f, const float* __restrict__ c2f,
    const float* __restrict__ W2mp, const float* __restrict__ WN,
    const float* __restrict__ n1, const float* __restrict__ n2,
    const float* __restrict__ m1, const float* __restrict__ m2,
    float* __restrict__ cosM,
    float* __restrict__ part, float* __restrict__ part2){
  const int b = blockIdx.x;
  const int itile = blockIdx.y >> 1;       // 0..31
  const int jh = blockIdx.y & 1;           // j-half
  const int i0 = itile*4;
  const int t = threadIdx.x;
  const int jl = t & 63;
  const int ph = (t>>6) & 1;
  const int row = t>>7;                    // 0..3
  const int j  = jh*64 + jl;
  const int phu  = __builtin_amdgcn_readfirstlane(ph);
  const int rowu = __builtin_amdgcn_readfirstlane(row);

  // LDS pool: sA (12KB) + sB 2 bufs (32KB) = 44KB → 2 blocks/CU.
  // sP2 (side1 combine, 32KB) aliases sB post-loop (barrier-separated).
  __shared__ __align__(16) float pool[3072 + 2*BUFQ];
  float* sA = pool;                        // [4][768]
  float* sB = pool + 3072;                 // [2][64][64] swizzled
  float* sP2 = pool + 3072;                // alias: [4][64][16][2]

  const float4* gball = (const float4*)(c2f + (size_t)b*Ln*Hn);
  const int sr0 = t>>4, sq = t&15;         // staging decomposition
  const int swz0 = (sq ^ (sr0&15))<<2;     // same for row sr0 and sr0+32

  // ---- prologue: stage A-rows + chunk 0 of B ----
  {
    const float4* arow4 = (const float4*)(c1f + ((size_t)(b*Ln+i0))*Hn);
    float4* sA4 = (float4*)sA;
    for(int idx=t; idx<Hn; idx+=512) sA4[idx] = arow4[idx];  // 4 rows = 768 float4
    float4 v0 = gball[(size_t)(jh*64 + sr0     )*(Hn/4) + sq];
    float4 v1 = gball[(size_t)(jh*64 + sr0 + 32)*(Hn/4) + sq];
    *(float4*)(sB + (size_t)sr0*64      + swz0) = v0;
    *(float4*)(sB + (size_t)(sr0+32)*64 + swz0) = v1;
  }
  __syncthreads();

  const float* w2b = W2mp + phu*8;      // scalar (s_load) path
  const float4* aR = (const float4*)(sA + rowu*Hn);
  const int jx = jl & 15;
  const float* sBrow = sB + (size_t)jl*64;

  float acc[8];
#pragma unroll
  for(int pp=0;pp<8;pp++) acc[pp]=0.f;
  float dot=0.f;

  for(int c=0; c<NCH; ++c){
    // ---- issue next-chunk global loads (2 float4 in flight; consumed post-compute) ----
    float4 v0, v1;
    const bool more = (c+1 < NCH);
    if(more){
      v0 = gball[(size_t)(jh*64 + sr0     )*(Hn/4) + (c+1)*QCH + sq];
      v1 = gball[(size_t)(jh*64 + sr0 + 32)*(Hn/4) + (c+1)*QCH + sq];
    }
    // ---- compute this chunk from swizzled LDS ----
    const float* bbuf = sBrow + (c&1)*BUFQ;
#pragma unroll 2
    for(int hql=0; hql<QCH; ++hql){
      const int hq = c*QCH + hql;
      float4 a  = aR[hq];                                   // wave-uniform broadcast
      float4 bq = *(const float4*)(bbuf + ((hql ^ jx)<<2)); // swizzled read
#pragma unroll
      for(int d=0; d<4; ++d){
        float bv = (d==0)? bq.x : (d==1)? bq.y : (d==2)? bq.z : bq.w;
        float av = (d==0)? a.x  : (d==1)? a.y  : (d==2)? a.z  : a.w;
        const float* wr = w2b + (size_t)(hq*4+d)*Pn;
        float pr = av*bv;
        dot += pr;
#pragma unroll
        for(int pp=0;pp<8;pp++) acc[pp]=fmaf(wr[pp],pr,acc[pp]);
      }
    }
    if(more){
      // write buf[(c+1)&1]: its last readers (chunk c-1) finished at the previous
      // barrier; current readers use buf[c&1]. One barrier per chunk.
      *(float4*)(sB + ((c+1)&1)*BUFQ + (size_t)sr0*64      + swz0) = v0;
      *(float4*)(sB + ((c+1)&1)*BUFQ + (size_t)(sr0+32)*64 + swz0) = v1;
      __syncthreads();
    }
  }
  __syncthreads();              // last compute done; sB free → alias sP2

  const int iR = i0 + row;

  // ---- fused cosine write (ph==0 threads own it) ----
  if(ph==0){
    float nj = fmaxf(n2[b*Ln+j], EPSF);
    cosM[((size_t)(b*Ln+iR))*Ln + j] = dot/(fmaxf(n1[b*Ln+iR],EPSF)*nj);
  }

  // ---- normalize e in place ----
#pragma unroll
  for(int pp=0;pp<8;pp++){
    int p = ph*8+pp;
    float sl = sqrtf(fmaxf(WN[wnIdx(1,2,b,p,j)],0.f));
    float sr = sqrtf(fmaxf(WN[wnIdx(0,2,b,p,iR)],0.f));
    acc[pp] = acc[pp]/fmaxf(sr*sl,EPSF);
  }

  // ---- side0 partial: in-wave reduce over 64 jl (mask2); lanes ARE jl ----
  {
    const bool valid = (m2[b*Ln+j]!=0.f);
#pragma unroll
    for(int pp=0;pp<8;pp++){
      float vmax = valid? acc[pp] : NINF;
      float vsum = valid? acc[pp] : 0.f;
      vmax = wred_max(vmax);
      vsum = wred_sum(vsum);
      if(jl==0){
        size_t o = (((size_t)(b*Ln+iR))*Pn + ph*8+pp)*4 + jh*2;
        part2[o]   = vmax;
        part2[o+1] = vsum;
      }
    }
  }

  // ---- side1 partial: masked per-row values → aliased LDS → combine over 4 rows ----
  {
    float mr = m1[b*Ln+iR];
#pragma unroll
    for(int pp=0;pp<8;pp++){
      int p = ph*8+pp;
      size_t o = ((size_t)((row*64 + jl)*16 + p))*2;
      sP2[o]   = (mr!=0.f)? acc[pp] : NINF;
      sP2[o+1] = (mr!=0.f)? acc[pp] : 0.f;
    }
  }
  __syncthreads();
  for(int it=t; it<64*16; it+=512){
    int jl2 = it>>4, p2 = it&15;
    float M=NINF, S=0.f;
#pragma unroll
    for(int r=0;r<4;r++){
      size_t o = ((size_t)((r*64+jl2)*16 + p2))*2;
      M = fmaxf(M, sP2[o]);
      S += sP2[o+1];
    }
    int j2 = jh*64 + jl2;
    size_t o = ((((size_t)(b*Ln+j2))*Pn + p2)*32 + itile)*2;
    part[o]=M; part[o+1]=S;
  }
}

// ---------------- k_mm2: combine side1 partials (32 i-tiles) + side0 (2 j-halves) ----------------
__global__ __launch_bounds__(256) void k_mm2(
    const float* __restrict__ part, const float* __restrict__ part2,
    const int* __restrict__ lens,
    float* __restrict__ mvmax, float* __restrict__ mvmean){
  int g = blockIdx.x*256 + threadIdx.x;   // 16384 = B*L*P
  int b = g>>11;
  // side 1: over 32 i-tiles
  const float4* q = (const float4*)(part + (size_t)g*64);
  float mx = NINF, sm = 0.f;
#pragma unroll
  for(int k=0;k<16;k++){
    float4 v = q[k];
    mx = fmaxf(mx, fmaxf(v.x, v.z));
    sm += v.y + v.w;
  }
  int len1 = min(max(lens[b],1),Ln);
  size_t o1 = (size_t)Bn*Ln*Pn + g;       // side 1 block of mv arrays
  mvmax[o1] = mx;
  mvmean[o1] = sm/(float)len1;
  // side 0: over 2 j-halves
  float4 v2 = *(const float4*)(part2 + (size_t)g*4);
  int len2 = min(max(lens[8+b],1),Ln);
  mvmax[g]  = fmaxf(v2.x, v2.z);
  mvmean[g] = (v2.y + v2.w)/(float)len2;
}

// ---------------- k_fin: attention + all 102 features; p-in-lane Phase B ----------------
// grid (16, Ln/2): x = side*8+b → XCD = b
__global__ __launch_bounds__(256) void k_fin(
    const float* __restrict__ c1f, const float* __restrict__ c2f,
    const float* __restrict__ cosM,
    const float* __restrict__ n1, const float* __restrict__ n2,
    const float* __restrict__ wn, const float* __restrict__ W2T,
    const float* __restrict__ mvmax, const float* __restrict__ mvmean,
    const int* __restrict__ lens,
    const float* __restrict__ m1, const float* __restrict__ m2,
    float* __restrict__ out){
  const int x = blockIdx.x, side = x>>3, b = x&7;
  const int r0 = blockIdx.y*2;
  const int t = threadIdx.x, w = t>>6, l = t&63;
  const float* selfF  = side? c2f : c1f;
  const float* otherF = side? c1f : c2f;
  const float* nSelf  = side? n2 : n1;
  const float* nOther = side? n1 : n2;
  const float* mInner = side? m1 : m2;
  const float* mSelfm = side? m2 : m1;
  int lenI = side? lens[b]    : lens[8+b];
  int lpO  = side? lens[16+b] : lens[24+b];
  lenI = min(max(lenI,1),Ln);
  lpO  = min(max(lpO,0),Ln-1);

  __shared__ float cS[2*Ln];
  __shared__ float mS[Ln];
  __shared__ float sV1[2][Hn];
  __shared__ float sF[Hn], sB[Hn];
  __shared__ float sAS[2][Hn], sAM[2][Hn];
  __shared__ float red[8][4];

  // ---- stage ----
  {
    if(side==0){
      const float* crow = cosM + ((size_t)(b*Ln+r0))*Ln;
      for(int idx=t; idx<2*Ln; idx+=256) cS[idx]=crow[idx];
    } else {
      int jj = t&127, rp = t>>7;   // transposed read: cos^T[r][j] = cosM[j][r]
      cS[rp*Ln+jj] = cosM[((size_t)(b*Ln+jj))*Ln + r0+rp];
    }
    if(t<Ln) mS[t]=mInner[b*Ln+t];
    const float4* s4 = (const float4*)(selfF + ((size_t)(b*Ln+r0))*Hn);
    float4* d4 = (float4*)sV1;
    for(int idx=t; idx<2*Hn/4; idx+=256) d4[idx]=s4[idx];
    const float4* f4 = (const float4*)(otherF + ((size_t)(b*Ln+lpO))*Hn);
    const float4* b4 = (const float4*)(otherF + ((size_t)(b*Ln))*Hn);
    if(t<Hn/4){ ((float4*)sF)[t]=f4[t]; ((float4*)sB)[t]=b4[t]; }
  }
  __syncthreads();

  // ---- attention accumulation (2 rows, h = 3t..3t+2) ----
  float aS0[3]={0,0,0}, aS1[3]={0,0,0}, aM0[3]={NINF,NINF,NINF}, aM1[3]={NINF,NINF,NINF};
  {
    const float* src = otherF + (size_t)b*Ln*Hn;
#pragma unroll 4
    for(int jj=0; jj<Ln; ++jj){
      float3 vk = ((const float3*)(src + (size_t)jj*Hn))[t];
      float msk = mS[jj];
      float c0=cS[jj], c1v=cS[Ln+jj];
      aS0[0]=fmaf(vk.x,c0 ,aS0[0]); aS0[1]=fmaf(vk.y,c0 ,aS0[1]); aS0[2]=fmaf(vk.z,c0 ,aS0[2]);
      aS1[0]=fmaf(vk.x,c1v,aS1[0]); aS1[1]=fmaf(vk.y,c1v,aS1[1]); aS1[2]=fmaf(vk.z,c1v,aS1[2]);
      if(msk!=0.f){
        aM0[0]=fmaxf(aM0[0],vk.x*c0 ); aM0[1]=fmaxf(aM0[1],vk.y*c0 ); aM0[2]=fmaxf(aM0[2],vk.z*c0 );
        aM1[0]=fmaxf(aM1[0],vk.x*c1v); aM1[1]=fmaxf(aM1[1],vk.y*c1v); aM1[2]=fmaxf(aM1[2],vk.z*c1v);
      }
    }
  }

  // ---- softmax over h (2 rows); -1e30 masking => fully-masked rows → uniform ----
  {
    float lm0 = fmaxf(fmaxf(aS0[0],aS0[1]),aS0[2]);
    float lm1 = fmaxf(fmaxf(aS1[0],aS1[1]),aS1[2]);
    lm0 = wred_max(lm0); lm1 = wred_max(lm1);
    if(l==0){ red[0][w]=lm0; red[1][w]=lm1; }
  }
  __syncthreads();
  float bm0 = fmaxf(fmaxf(red[0][0],red[0][1]),fmaxf(red[0][2],red[0][3]));
  float bm1 = fmaxf(fmaxf(red[1][0],red[1][1]),fmaxf(red[1][2],red[1][3]));
  __syncthreads();
  float ev0[3], ev1[3];
  {
    float es0=0.f, es1=0.f;
#pragma unroll
    for(int k=0;k<3;k++){
      ev0[k]=expf(aS0[k]-bm0); es0+=ev0[k];
      ev1[k]=expf(aS1[k]-bm1); es1+=ev1[k];
    }
    es0 = wred_sum(es0); es1 = wred_sum(es1);
    if(l==0){ red[0][w]=es0; red[1][w]=es1; }
  }
  __syncthreads();
  {
    float smr0 = mSelfm[b*Ln+r0], smr1 = mSelfm[b*Ln+r0+1];
    float bs0 = red[0][0]+red[0][1]+red[0][2]+red[0][3];
    float bs1 = red[1][0]+red[1][1]+red[1][2]+red[1][3];
    float inv0 = 1.f/fmaxf(bs0,EPSF), inv1 = 1.f/fmaxf(bs1,EPSF);
    const float u = 1.f/(float)Hn;
#pragma unroll
    for(int k=0;k<3;k++){
      sAS[0][3*t+k] = (smr0!=0.f)? ev0[k]*inv0 : u;
      sAS[1][3*t+k] = (smr1!=0.f)? ev1[k]*inv1 : u;
      sAM[0][3*t+k] = aM0[k];
      sAM[1][3*t+k] = aM1[k];
    }
  }
  __syncthreads();

  // ---- Phase A (waves 0-1) + Phase C (wave 2): independent, no barrier ----
  if(w<2){
    int rr = w;
    float cmx=NINF, csm=0.f;
    float ca = cS[rr*Ln + l], cb = cS[rr*Ln + l + 64];
    if(mS[l]!=0.f){ cmx=ca; csm=ca; }
    if(mS[l+64]!=0.f){ cmx=fmaxf(cmx,cb); csm+=cb; }
    cmx = wred_max(cmx); csm = wred_sum(csm);
    if(l==0){
      float* op = out + ((size_t)((b*2+side)*Ln + r0+rr))*Dn;
      op[0] = cmx;
      op[1] = csm/(float)lenI;
    }
  } else if(w==2){
    int rr = l>>5, qq = l&31, p = qq&15;
    size_t o = ((size_t)((side*Bn+b)*Ln + r0+rr))*Pn + p;
    float* op = out + ((size_t)((b*2+side)*Ln + r0+rr))*Dn;
    if(qq<16) op[36+p] = mvmax[o];
    else      op[52+p] = mvmean[o];
  }

  // ---- Phase B: wave w handles mi=w for both rows; lane = (p, hq) ----
  {
    const int Xids[4] = {0,1,3,4};
    const int offS[4] = {2,19,68,85};
    const int X = Xids[w], offs = offS[w];
    const bool dyn = (w>=2);
    const int p = l&15, hq = l>>4;
    const int h0 = hq*192;
    const float* w2p = W2T + ((size_t)X*Hn)*Pn + p;
    float acc0=0.f, acc1=0.f, s00=0.f, s01=0.f;
    float sn0=0.f, sn1=0.f, sna0=0.f, sna1=0.f;
    if(!dyn){
      const float* bvp = (w==0)? sF : sB;
#pragma unroll 4
      for(int hh=0; hh<192; ++hh){
        int h = h0+hh;
        float w2v = w2p[(size_t)h*Pn];
        float bv = bvp[h];
        float pr0 = sV1[0][h]*bv, pr1 = sV1[1][h]*bv;
        acc0 = fmaf(w2v,pr0,acc0); acc1 = fmaf(w2v,pr1,acc1);
        s00 += pr0; s01 += pr1;
      }
    } else {
      const float* bv0p = (w==2)? sAS[0] : sAM[0];
      const float* bv1p = (w==2)? sAS[1] : sAM[1];
#pragma unroll 4
      for(int hh=0; hh<192; ++hh){
        int h = h0+hh;
        float w2v = w2p[(size_t)h*Pn];
        float bv0 = bv0p[h], bv1 = bv1p[h];
        float pr0 = sV1[0][h]*bv0, pr1 = sV1[1][h]*bv1;
        float bb0 = bv0*bv0, bb1 = bv1*bv1;
        acc0 = fmaf(w2v,pr0,acc0); acc1 = fmaf(w2v,pr1,acc1);
        sna0 = fmaf(w2v,bb0,sna0); sna1 = fmaf(w2v,bb1,sna1);
        s00 += pr0; s01 += pr1;
        sn0 += bb0; sn1 += bb1;
      }
    }
    acc0 = qred_sum(acc0); acc1 = qred_sum(acc1);
    s00  = qred_sum(s00);  s01  = qred_sum(s01);
    if(dyn){
      sna0 = qred_sum(sna0); sna1 = qred_sum(sna1);
      sn0  = qred_sum(sn0);  sn1  = qred_sum(sn1);
    }
#pragma unroll
    for(int rr=0; rr<2; ++rr){
      const int r = r0+rr;
      float accv = rr? acc1 : acc0;
      float s0v  = rr? s01  : s00;
      float snav = rr? sna1 : sna0;
      float snv  = rr? sn1  : sn0;
      float* op = out + ((size_t)((b*2+side)*Ln + r))*Dn;
      if(l<16){
        float wa = fmaxf(wn[wnIdx(side,X,b,l,r)],0.f);
        float wb = dyn? fmaxf(snav,0.f)
                      : fmaxf(wn[wnIdx(1-side,X,b,l,(w==0? lpO:0))],0.f);
        float mul = accv/(fmaxf(sqrtf(wa),EPSF)*fmaxf(sqrtf(wb),EPSF));
        op[offs+1+l] = mul;
      }
      if(l==0){
        float nb = dyn? sqrtf(fmaxf(snv,0.f)) : nOther[b*Ln + (w==0? lpO : 0)];
        float nv1 = nSelf[b*Ln+r];
        op[offs] = s0v/(fmaxf(nv1,EPSF)*fmaxf(nb,EPSF));
      }
    }
  }
}

extern "C" void kernel_launch(void* const* d_in, const int* in_sizes, int n_in,
                              void* d_out, int out_size, void* d_ws, size_t ws_size,
                              hipStream_t stream) {
  const float* ctx1 = (const float*)d_in[0];
  const float* m1   = (const float*)d_in[1];
  const float* ctx2 = (const float*)d_in[2];
  const float* m2   = (const float*)d_in[3];
  const float* wff  = (const float*)d_in[4];
  const float* wfb  = (const float*)d_in[5];
  const float* wmp  = (const float*)d_in[6];
  const float* watt = (const float*)d_in[7];
  const float* wmatt= (const float*)d_in[8];
  float* out = (float*)d_out;
  float* W = (float*)d_ws;
  int* lens = (int*)(W + OFF_LENS);

  k_prep<<<dim3(8 + (5*Pn*Hn)/256), 256, 0, stream>>>(m1,m2,wff,wfb,wmp,watt,wmatt,
      W+OFF_W2T, lens);
  k_rows<<<dim3(Ln,Bn,2), 256, 0, stream>>>(ctx1,m1,ctx2,m2, W+OFF_W2T,
      W+OFF_C1F, W+OFF_C2F, W+OFF_N1, W+OFF_N2, W+OFF_WN);
  k_mm<<<dim3(Bn, 64), 512, 0, stream>>>(W+OFF_C1F, W+OFF_C2F,
      W+OFF_W2T + (size_t)2*Hn*Pn, W+OFF_WN, W+OFF_N1, W+OFF_N2,
      m1, m2, W+OFF_COS, W+OFF_PART, W+OFF_PART2);
  k_mm2<<<dim3((Bn*Ln*Pn)/256), 256, 0, stream>>>(W+OFF_PART, W+OFF_PART2, lens,
      W+OFF_MVMAX, W+OFF_MVMEAN);
  k_fin<<<dim3(16, Ln/2), 256, 0, stream>>>(W+OFF_C1F, W+OFF_C2F, W+OFF_COS,
      W+OFF_N1, W+OFF_N2, W+OFF_WN, W+OFF_W2T, W+OFF_MVMAX, W+OFF_MVMEAN,
      lens, m1, m2, out);
}